// Round 22
// baseline (412.948 us; speedup 1.0000x reference)
//
#include <hip/hip_runtime.h>
#include <hip/hip_bf16.h>
#include <cstdint>

#define HID 512
#define K1P 288   // unfolded feat K padded 272 -> 288 (fallback path)
#define K1F 160   // folded feat K: 16 + 136 upper-tri, padded 152 -> 160 (5 x BK32)
#define NBG 96    // scatter blocks per XCD group

typedef __attribute__((ext_vector_type(8))) short bf16x8;
typedef __attribute__((ext_vector_type(4))) float f32x4;
typedef __attribute__((ext_vector_type(2))) long i64x2;

__device__ __forceinline__ short f2bf(float x) {
    __hip_bfloat16 h = __float2bfloat16(x);
    return *(short*)&h;
}
__device__ __forceinline__ unsigned char f2fp8(float x) {
    int p = __builtin_amdgcn_cvt_pk_fp8_f32(x, x, 0, false);
    return (unsigned char)(p & 0xff);
}
__device__ __forceinline__ float silu(float x) {
    return x * (1.0f / (1.0f + __expf(-x)));
}
__device__ __forceinline__ void gl_lds16(const void* src, void* dst) {
    __builtin_amdgcn_global_load_lds(
        (const __attribute__((address_space(1))) void*)src,
        (__attribute__((address_space(3))) void*)dst, 16, 0, 0);
}
// bijective XCD swizzle (m204)
__device__ __forceinline__ int xcd_swz(int bid, int nwg) {
    int q = nwg >> 3, r = nwg & 7;
    int xcd = bid & 7, i = bid >> 3;
    int base = (xcd < r) ? xcd * (q + 1) : r * (q + 1) + (xcd - r) * q;
    return base + i;
}
// inverse upper-triangle index: g in [0,136) -> (a,b) with a<=b
__device__ __forceinline__ void tri_ab(int g, int& a, int& b) {
    int aa = 0, rem = g;
    while (rem >= 16 - aa) { rem -= 16 - aa; ++aa; }
    a = aa; b = aa + rem;
}

// ---------- 1) histogram (int4-vectorized) ----------
__global__ __launch_bounds__(256) void hist_kernel(
    const int* __restrict__ idx, int* __restrict__ counts, int nEdges, int vec4)
{
    int q = blockIdx.x * 256 + threadIdx.x;
    if (vec4) {
        int nq = nEdges >> 2;
        if (q < nq) {
            int4 v = ((const int4*)idx)[q];
            atomicAdd(&counts[v.x], 1); atomicAdd(&counts[v.y], 1);
            atomicAdd(&counts[v.z], 1); atomicAdd(&counts[v.w], 1);
        }
    } else {
        if (q < nEdges) atomicAdd(&counts[idx[q]], 1);
    }
}

// ---------- 2) scan, pass 1 ----------
__global__ __launch_bounds__(1024) void scan1_kernel(
    const int* __restrict__ counts, int* __restrict__ starts,
    int* __restrict__ blockSum, int n)
{
    __shared__ int wsum[16];
    int t = threadIdx.x, lane = t & 63, wid = t >> 6;
    int i = blockIdx.x * 1024 + t;
    int v = (i < n) ? counts[i] : 0;
    int incl = v;
    #pragma unroll
    for (int off = 1; off < 64; off <<= 1) {
        int u = __shfl_up(incl, off);
        if (lane >= off) incl += u;
    }
    if (lane == 63) wsum[wid] = incl;
    __syncthreads();
    if (t < 16) {
        int s = wsum[t];
        #pragma unroll
        for (int off = 1; off < 16; off <<= 1) {
            int u = __shfl_up(s, off);
            if (t >= off) s += u;
        }
        wsum[t] = s;
    }
    __syncthreads();
    int woff = (wid == 0) ? 0 : wsum[wid - 1];
    if (i < n) starts[i] = woff + incl - v;
    if (t == 0) blockSum[blockIdx.x] = wsum[15];
}

// ---------- 2b) scan block sums ----------
__global__ __launch_bounds__(1024) void scan2_kernel(
    const int* __restrict__ blockSum, int* __restrict__ blockOff,
    int* __restrict__ starts, int nb, int n)
{
    __shared__ int arr[1024];
    int t = threadIdx.x;
    int v = (t < nb) ? blockSum[t] : 0;
    arr[t] = v;
    __syncthreads();
    #pragma unroll
    for (int off = 1; off < 1024; off <<= 1) {
        int x = (t >= off) ? arr[t - off] : 0;
        __syncthreads();
        arr[t] += x;
        __syncthreads();
    }
    if (t < nb) blockOff[t] = arr[t] - v;
    if (t == 0) starts[n] = arr[nb - 1];
}

// ---------- 2c) add offsets ----------
__global__ __launch_bounds__(1024) void scan3_kernel(
    int* __restrict__ starts, int* __restrict__ cursor,
    const int* __restrict__ blockOff, int n)
{
    int i = blockIdx.x * 1024 + threadIdx.x;
    if (i < n) {
        int s = starts[i] + blockOff[blockIdx.x];
        starts[i] = s;
        cursor[i] = s;
    }
}

// ---------- 3) XCD-partitioned scatter (R20 verbatim) ----------
__global__ __launch_bounds__(256) void scatter2_kernel(
    const float* __restrict__ R, const int* __restrict__ idx,
    int* __restrict__ cursor, float4* __restrict__ sorted, int nEdges, int nAtoms)
{
    int g  = blockIdx.x & 7;
    int gb = blockIdx.x >> 3;
    int per = (nAtoms + 7) >> 3;
    int lo = g * per;
    int hi = lo + per; if (hi > nAtoms) hi = nAtoms;

    auto emit = [&](int i, int j) {
        if (i < lo || i >= hi) return;
        float rix = R[3*(size_t)i], riy = R[3*(size_t)i+1], riz = R[3*(size_t)i+2];
        float rjx = R[3*(size_t)j], rjy = R[3*(size_t)j+1], rjz = R[3*(size_t)j+2];
        float dx = rjx - rix, dy = rjy - riy, dz = rjz - riz;
        float r = sqrtf(dx*dx + dy*dy + dz*dz);
        float inv = 1.0f / (r + 1e-8f);
        int pos = atomicAdd(&cursor[i], 1);
        sorted[pos] = make_float4(r, dx*inv, dy*inv, dz*inv);
    };

    if ((nEdges & 3) == 0) {
        int nq = nEdges >> 2;
        const int4* i4p = (const int4*)idx;
        const int4* j4p = (const int4*)(idx + nEdges);
        for (int q = gb * 256 + threadIdx.x; q < nq; q += NBG * 256) {
            int4 iv = i4p[q], jv = j4p[q];
            emit(iv.x, jv.x); emit(iv.y, jv.y);
            emit(iv.z, jv.z); emit(iv.w, jv.w);
        }
    } else {
        for (int e = gb * 256 + threadIdx.x; e < nEdges; e += NBG * 256)
            emit(idx[e], idx[nEdges + e]);
    }
}

// ---------- 4) segmented reduce + fused folded-feat (R18 verbatim) ----------
__global__ __launch_bounds__(256) void accum_kernel(
    const float4* __restrict__ sorted, const int* __restrict__ starts,
    const float* __restrict__ centers, const float* __restrict__ width,
    float* __restrict__ M0M1, short* __restrict__ feat16,
    int nAtoms, int useFeat)
{
    __shared__ float sm[4][64];
    int wv = threadIdx.x >> 6, lane = threadIdx.x & 63;
    int atom = blockIdx.x * 4 + wv;
    if (atom >= nAtoms) return;
    int s = starts[atom], e = starts[atom + 1];
    int k = lane >> 2, c = lane & 3;
    float ck = centers[k];
    float w = width[0];
    float inv2w2 = 1.0f / (2.0f * w * w);
    float acc = 0.0f;
    auto term = [&](float4 v) {
        float diff = v.x - ck;
        float b = __expf(-diff * diff * inv2w2);
        float comp = (c == 0) ? 1.0f : ((c == 1) ? v.y : ((c == 2) ? v.z : v.w));
        return b * comp;
    };
    int p = s;
    for (; p + 3 < e; p += 4) {
        float4 v0 = sorted[p];
        float4 v1 = sorted[p + 1];
        float4 v2 = sorted[p + 2];
        float4 v3 = sorted[p + 3];
        acc += term(v0); acc += term(v1); acc += term(v2); acc += term(v3);
    }
    for (; p < e; ++p) acc += term(sorted[p]);

    if (!useFeat) {
        M0M1[(size_t)atom * 64 + lane] = acc;
        return;
    }
    sm[wv][lane] = acc;
    asm volatile("s_waitcnt lgkmcnt(0)" ::: "memory");
    short* frow = feat16 + (size_t)atom * K1F;
    #pragma unroll
    for (int q = 0; q < 3; ++q) {
        int idx5 = q * 64 + lane;
        if (idx5 >= K1F) break;
        float val;
        if (idx5 < 16) {
            val = sm[wv][4 * idx5];
        } else if (idx5 < 152) {
            int a, b;
            tri_ab(idx5 - 16, a, b);
            val = sm[wv][4*a+1] * sm[wv][4*b+1]
                + sm[wv][4*a+2] * sm[wv][4*b+2]
                + sm[wv][4*a+3] * sm[wv][4*b+3];
        } else {
            val = 0.0f;
        }
        frow[idx5] = f2bf(val);
    }
}

// ---------- W -> bf16 transposed (fallback W1t + W2t) ----------
__global__ __launch_bounds__(256) void convW_kernel(
    const float* __restrict__ W, short* __restrict__ Wt, int K, int Kpad, int N)
{
    int n = blockIdx.x * 256 + threadIdx.x;
    int k = blockIdx.y;
    if (n >= N) return;
    float v = (k < K) ? W[(size_t)k * N + n] : 0.0f;
    Wt[(size_t)n * Kpad + k] = f2bf(v);
}

// ---------- W1 -> folded bf16 transposed W1f[n][160] ----------
__global__ __launch_bounds__(256) void convW1f_kernel(
    const float* __restrict__ W, short* __restrict__ Wf, int N)
{
    int n = blockIdx.x * 256 + threadIdx.x;
    int k = blockIdx.y;
    if (n >= N) return;
    float v;
    if (k < 16) {
        v = W[(size_t)k * N + n];
    } else if (k < 152) {
        int a, b;
        tri_ab(k - 16, a, b);
        v = W[(size_t)(16 + a*16 + b) * N + n];
        if (b > a) v += W[(size_t)(16 + b*16 + a) * N + n];
    } else {
        v = 0.0f;
    }
    Wf[(size_t)n * K1F + k] = f2bf(v);
}

// ---------- W2 -> fp8 e4m3 transposed, pre-scaled x16: W2f8[n][512] ----------
__global__ __launch_bounds__(256) void convW2f8_kernel(
    const float* __restrict__ W, unsigned char* __restrict__ Wf, int N)
{
    int n = blockIdx.x * 256 + threadIdx.x;
    int k = blockIdx.y;
    if (n >= N) return;
    Wf[(size_t)n * HID + k] = f2fp8(W[(size_t)k * N + n] * 16.0f);
}

// ============ GEMM1 fallback (R10 verbatim, bf16 h1) ============
__global__ __launch_bounds__(256, 2) void gemm1_mfma(
    const float* __restrict__ M0M1, const short* __restrict__ W1t,
    const float* __restrict__ bias, short* __restrict__ C, int M, int nwg)
{
    __shared__ float MsT[64][128];
    __shared__ short Asl[2][4096];
    __shared__ short Bsl[4][4096];
    int t = threadIdx.x;
    int w = t >> 6, lane = t & 63;
    int wr = w >> 1, wc = w & 1;
    int li = lane & 15, lg = lane >> 4;
    int lin = xcd_swz(blockIdx.x, nwg);
    int row0 = (lin >> 2) * 128;
    int col0 = (lin & 3) * 128;

    {
        int mrow = t >> 1, mo = (t & 1) * 32;
        int gm = row0 + mrow; if (gm > M - 1) gm = M - 1;
        const float4* src = (const float4*)(M0M1 + (size_t)gm * 64 + mo);
        #pragma unroll
        for (int q = 0; q < 8; ++q) {
            float4 v = src[q];
            int c0 = mo + q * 4;
            MsT[c0+0][mrow] = v.x; MsT[c0+1][mrow] = v.y;
            MsT[c0+2][mrow] = v.z; MsT[c0+3][mrow] = v.w;
        }
    }
    __syncthreads();

    auto stageA = [&](int kt, int buf) {
        #pragma unroll
        for (int p = 0; p < 2; ++p) {
            int cell = p * 256 + t;
            int k8 = cell >> 7, row = cell & 127;
            int kbase = kt * 32 + k8 * 8;
            bf16x8 v;
            if (kbase < 16) {
                #pragma unroll
                for (int j = 0; j < 8; ++j) v[j] = f2bf(MsT[4*(kbase+j)][row]);
            } else if (kbase < 272) {
                int g = kbase - 16, a = g >> 4, b0 = g & 15;
                float ax = MsT[4*a+1][row], ay = MsT[4*a+2][row], az = MsT[4*a+3][row];
                #pragma unroll
                for (int j = 0; j < 8; ++j) {
                    int b = b0 + j;
                    v[j] = f2bf(ax*MsT[4*b+1][row] + ay*MsT[4*b+2][row] + az*MsT[4*b+3][row]);
                }
            } else {
                #pragma unroll
                for (int j = 0; j < 8; ++j) v[j] = 0;
            }
            *(bf16x8*)&Asl[buf][cell * 8] = v;
        }
    };
    auto stageB = [&](int kt, int buf) {
        #pragma unroll
        for (int p = 0; p < 2; ++p) {
            int cell = p * 256 + t;
            int k8 = cell >> 7, col = cell & 127;
            const short* src = W1t + (size_t)(col0 + col) * K1P + kt*32 + k8*8;
            gl_lds16(src, &Bsl[buf][(p * 256 + w * 64) * 8]);
        }
    };

    f32x4 acc[4][4] = {};
    const int NS = K1P / 32;
    stageA(0, 0);
    stageB(0, 0); stageB(1, 1); stageB(2, 2);

    #pragma unroll
    for (int s = 0; s < NS; ++s) {
        if (s <= NS - 3)      asm volatile("s_waitcnt vmcnt(4) lgkmcnt(0)\n\ts_barrier" ::: "memory");
        else if (s == NS - 2) asm volatile("s_waitcnt vmcnt(2) lgkmcnt(0)\n\ts_barrier" ::: "memory");
        else                  asm volatile("s_waitcnt vmcnt(0) lgkmcnt(0)\n\ts_barrier" ::: "memory");
        if (s + 3 < NS) stageB(s + 3, (s + 3) & 3);
        bf16x8 af[4], bfr[4];
        #pragma unroll
        for (int m = 0; m < 4; ++m)
            af[m] = *(const bf16x8*)&Asl[s & 1][(lg*128 + wr*64 + m*16 + li) * 8];
        #pragma unroll
        for (int n = 0; n < 4; ++n)
            bfr[n] = *(const bf16x8*)&Bsl[s & 3][(lg*128 + wc*64 + n*16 + li) * 8];
        if (s + 1 < NS) stageA(s + 1, (s + 1) & 1);
        __builtin_amdgcn_s_setprio(1);
        #pragma unroll
        for (int m = 0; m < 4; ++m)
            #pragma unroll
            for (int n = 0; n < 4; ++n)
                acc[m][n] = __builtin_amdgcn_mfma_f32_16x16x32_bf16(af[m], bfr[n], acc[m][n], 0, 0, 0);
        __builtin_amdgcn_s_setprio(0);
    }

    float bv[4];
    #pragma unroll
    for (int n = 0; n < 4; ++n) bv[n] = bias[col0 + wc*64 + n*16 + li];
    #pragma unroll
    for (int m = 0; m < 4; ++m)
        #pragma unroll
        for (int r = 0; r < 4; ++r) {
            int row = row0 + wr*64 + m*16 + lg*4 + r;
            if (row >= M) continue;
            size_t base = (size_t)row * HID + col0 + wc*64 + li;
            #pragma unroll
            for (int n = 0; n < 4; ++n) {
                float cx = acc[m][n][r] + bv[n];
                C[base + n*16] = f2bf(silu(cx));
            }
        }
}

// ============ GEMM1 folded-feat (R18 struct) -> h1 in fp8 e4m3 ============
__global__ __launch_bounds__(256, 3) void gemm_feat(
    const short* __restrict__ F, const short* __restrict__ W1f,
    const float* __restrict__ bias, unsigned char* __restrict__ C, int M, int nwg)
{
    __shared__ short Asl[3][4096];
    __shared__ short Bsl[3][4096];
    int t = threadIdx.x;
    int w = t >> 6, lane = t & 63;
    int wr = w >> 1, wc = w & 1;
    int li = lane & 15, lg = lane >> 4;
    int lin = xcd_swz(blockIdx.x, nwg);
    int row0 = (lin >> 2) * 128;
    int col0 = (lin & 3) * 128;

    int rr = t & 127, k8h = t >> 7;
    int grA = row0 + rr; if (grA > M - 1) grA = M - 1;
    const short* aSrc0 = F + (size_t)grA * K1F + k8h * 8;
    const short* aSrc1 = aSrc0 + 16;
    const short* bSrc0 = W1f + (size_t)(col0 + rr) * K1F + k8h * 8;
    const short* bSrc1 = bSrc0 + 16;

    auto stage = [&](int kt, int buf) {
        gl_lds16(aSrc0 + kt * 32, &Asl[buf][(w * 64) * 8]);
        gl_lds16(aSrc1 + kt * 32, &Asl[buf][(256 + w * 64) * 8]);
        gl_lds16(bSrc0 + kt * 32, &Bsl[buf][(w * 64) * 8]);
        gl_lds16(bSrc1 + kt * 32, &Bsl[buf][(256 + w * 64) * 8]);
    };

    f32x4 acc[4][4] = {};
    const int NS = K1F / 32;
    stage(0, 0); stage(1, 1);

    #pragma unroll
    for (int s = 0; s < NS; ++s) {
        if (s < NS - 1) asm volatile("s_waitcnt vmcnt(4)\n\ts_barrier" ::: "memory");
        else            asm volatile("s_waitcnt vmcnt(0)\n\ts_barrier" ::: "memory");
        if (s + 2 < NS) stage(s + 2, (s + 2) % 3);
        bf16x8 af[4], bfr[4];
        #pragma unroll
        for (int m = 0; m < 4; ++m)
            af[m] = *(const bf16x8*)&Asl[s % 3][(lg*128 + wr*64 + m*16 + li) * 8];
        #pragma unroll
        for (int n = 0; n < 4; ++n)
            bfr[n] = *(const bf16x8*)&Bsl[s % 3][(lg*128 + wc*64 + n*16 + li) * 8];
        __builtin_amdgcn_s_setprio(1);
        #pragma unroll
        for (int m = 0; m < 4; ++m)
            #pragma unroll
            for (int n = 0; n < 4; ++n)
                acc[m][n] = __builtin_amdgcn_mfma_f32_16x16x32_bf16(af[m], bfr[n], acc[m][n], 0, 0, 0);
        __builtin_amdgcn_s_setprio(0);
    }

    float bv[4];
    #pragma unroll
    for (int n = 0; n < 4; ++n) bv[n] = bias[col0 + wc*64 + n*16 + li];
    #pragma unroll
    for (int m = 0; m < 4; ++m)
        #pragma unroll
        for (int r = 0; r < 4; ++r) {
            int row = row0 + wr*64 + m*16 + lg*4 + r;
            if (row >= M) continue;
            size_t base = (size_t)row * HID + col0 + wc*64 + li;
            #pragma unroll
            for (int n = 0; n < 4; ++n) {
                float cx = acc[m][n][r] + bv[n];
                C[base + n*16] = f2fp8(silu(cx));
            }
        }
}

// ============ GEMM2 fp8 v2: 128x128, BK=32, 4-buf/3-ahead, b128 frag reads ============
// LDS per buf: [k16][row][16B]; gl_lds dest = waveBase + lane*16 (linear).
// Fragment read: b128 of the full 16B k16-unit (same access shape as the
// conflict-free bf16 path; lanes lg,lg^1 broadcast-share), select 8B by lg&1.
__global__ __launch_bounds__(256, 6) void gemm2_fp8(
    const unsigned char* __restrict__ A, const unsigned char* __restrict__ W2f,
    const float* __restrict__ bias, const float* __restrict__ W3,
    const float* __restrict__ b3, const float* __restrict__ scale,
    const float* __restrict__ shift, const int* __restrict__ Z,
    float* __restrict__ out, int M, int nwg)
{
    __shared__ __align__(16) unsigned char Asl[4][4096];
    __shared__ __align__(16) unsigned char Bsl[4][4096];
    __shared__ float rsum[2][128];
    __shared__ float red[4];
    int t = threadIdx.x;
    int w = t >> 6, lane = t & 63;
    int wr = w >> 1, wc = w & 1;
    int li = lane & 15, lg = lane >> 4;
    int lin = xcd_swz(blockIdx.x, nwg);
    int row0 = (lin >> 2) * 128;
    int col0 = (lin & 3) * 128;

    int rr = t & 127, k16 = t >> 7;
    int grA = row0 + rr; if (grA > M - 1) grA = M - 1;
    const unsigned char* aSrc = A + (size_t)grA * HID + k16 * 16;
    const unsigned char* bSrc = W2f + (size_t)(col0 + rr) * HID + k16 * 16;

    auto stage = [&](int kt, int buf) {   // 2 gl_lds per thread
        gl_lds16(aSrc + kt * 32, &Asl[buf][w * 1024]);
        gl_lds16(bSrc + kt * 32, &Bsl[buf][w * 1024]);
    };

    f32x4 acc[4][4] = {};
    const int NS = HID / 32;   // 16
    stage(0, 0); stage(1, 1); stage(2, 2);   // 6 loads in flight

    int half = lg & 1;
    for (int s = 0; s < NS; ++s) {
        if (s <= NS - 3)      asm volatile("s_waitcnt vmcnt(4)\n\ts_barrier" ::: "memory");
        else if (s == NS - 2) asm volatile("s_waitcnt vmcnt(2)\n\ts_barrier" ::: "memory");
        else                  asm volatile("s_waitcnt vmcnt(0)\n\ts_barrier" ::: "memory");
        if (s + 3 < NS) stage(s + 3, (s + 3) & 3);
        long af[4], bfr[4];
        const unsigned char* Ab = &Asl[s & 3][(lg >> 1) * 2048 + (wr*64 + li) * 16];
        const unsigned char* Bb = &Bsl[s & 3][(lg >> 1) * 2048 + (wc*64 + li) * 16];
        #pragma unroll
        for (int m = 0; m < 4; ++m) {
            i64x2 v = *(const i64x2*)(Ab + m * 256);
            af[m] = half ? v[1] : v[0];
        }
        #pragma unroll
        for (int n = 0; n < 4; ++n) {
            i64x2 v = *(const i64x2*)(Bb + n * 256);
            bfr[n] = half ? v[1] : v[0];
        }
        __builtin_amdgcn_s_setprio(1);
        #pragma unroll
        for (int m = 0; m < 4; ++m)
            #pragma unroll
            for (int n = 0; n < 4; ++n)
                acc[m][n] = __builtin_amdgcn_mfma_f32_16x16x32_fp8_fp8(af[m], bfr[n], acc[m][n], 0, 0, 0);
        __builtin_amdgcn_s_setprio(0);
    }

    float bv[4], w3v[4];
    #pragma unroll
    for (int n = 0; n < 4; ++n) {
        int col = col0 + wc*64 + n*16 + li;
        bv[n]  = bias[col];
        w3v[n] = W3[col];
    }
    #pragma unroll
    for (int m = 0; m < 4; ++m)
        #pragma unroll
        for (int r = 0; r < 4; ++r) {
            float s = 0.f;
            #pragma unroll
            for (int n = 0; n < 4; ++n) {
                float cx = acc[m][n][r] * 0.0625f + bv[n];   // undo W2 x16 pre-scale
                s += silu(cx) * w3v[n];
            }
            #pragma unroll
            for (int off = 1; off < 16; off <<= 1) s += __shfl_xor(s, off);
            if (li == 0) rsum[wc][wr*64 + m*16 + lg*4 + r] = s;
        }
    __syncthreads();
    float e = 0.f;
    if (t < 128) {
        int row = row0 + t;
        if (row < M) {
            float v = rsum[0][t] + rsum[1][t];
            int z = Z[row];
            e = scale[z] * v;
            if ((lin & 3) == 0) e += scale[z] * b3[0] + shift[z];
        }
    }
    #pragma unroll
    for (int off = 32; off > 0; off >>= 1) e += __shfl_down(e, off);
    if (lane == 0) red[w] = e;
    __syncthreads();
    if (t == 0) atomicAdd(out, red[0] + red[1] + red[2] + red[3]);
}

// ============ GEMM2 bf16 fallback (R16 verbatim) ============
__global__ __launch_bounds__(256, 3) void gemm2_mfma(
    const short* __restrict__ A, const short* __restrict__ W2t,
    const float* __restrict__ bias, const float* __restrict__ W3,
    const float* __restrict__ b3, const float* __restrict__ scale,
    const float* __restrict__ shift, const int* __restrict__ Z,
    float* __restrict__ out, int M, int nwg)
{
    __shared__ short Asl[3][4096];
    __shared__ short Bsl[3][4096];
    __shared__ float rsum[2][128];
    __shared__ float red[4];
    int t = threadIdx.x;
    int w = t >> 6, lane = t & 63;
    int wr = w >> 1, wc = w & 1;
    int li = lane & 15, lg = lane >> 4;
    int lin = xcd_swz(blockIdx.x, nwg);
    int row0 = (lin >> 2) * 128;
    int col0 = (lin & 3) * 128;

    int rr = t & 127, k8h = t >> 7;
    int grA = row0 + rr; if (grA > M - 1) grA = M - 1;
    const short* aSrc0 = A + (size_t)grA * HID + k8h * 8;
    const short* aSrc1 = aSrc0 + 16;
    const short* bSrc0 = W2t + (size_t)(col0 + rr) * HID + k8h * 8;
    const short* bSrc1 = bSrc0 + 16;

    auto stage = [&](int kt, int buf) {
        gl_lds16(aSrc0 + kt * 32, &Asl[buf][(w * 64) * 8]);
        gl_lds16(aSrc1 + kt * 32, &Asl[buf][(256 + w * 64) * 8]);
        gl_lds16(bSrc0 + kt * 32, &Bsl[buf][(w * 64) * 8]);
        gl_lds16(bSrc1 + kt * 32, &Bsl[buf][(256 + w * 64) * 8]);
    };

    f32x4 acc[4][4] = {};
    const int NS = HID / 32;
    stage(0, 0); stage(1, 1);

    for (int s = 0; s < NS; ++s) {
        if (s < NS - 1) asm volatile("s_waitcnt vmcnt(4)\n\ts_barrier" ::: "memory");
        else            asm volatile("s_waitcnt vmcnt(0)\n\ts_barrier" ::: "memory");
        if (s + 2 < NS) stage(s + 2, (s + 2) % 3);
        bf16x8 af[4], bfr[4];
        #pragma unroll
        for (int m = 0; m < 4; ++m)
            af[m] = *(const bf16x8*)&Asl[s % 3][(lg*128 + wr*64 + m*16 + li) * 8];
        #pragma unroll
        for (int n = 0; n < 4; ++n)
            bfr[n] = *(const bf16x8*)&Bsl[s % 3][(lg*128 + wc*64 + n*16 + li) * 8];
        __builtin_amdgcn_s_setprio(1);
        #pragma unroll
        for (int m = 0; m < 4; ++m)
            #pragma unroll
            for (int n = 0; n < 4; ++n)
                acc[m][n] = __builtin_amdgcn_mfma_f32_16x16x32_bf16(af[m], bfr[n], acc[m][n], 0, 0, 0);
        __builtin_amdgcn_s_setprio(0);
    }

    float bv[4], w3v[4];
    #pragma unroll
    for (int n = 0; n < 4; ++n) {
        int col = col0 + wc*64 + n*16 + li;
        bv[n]  = bias[col];
        w3v[n] = W3[col];
    }
    #pragma unroll
    for (int m = 0; m < 4; ++m)
        #pragma unroll
        for (int r = 0; r < 4; ++r) {
            float s = 0.f;
            #pragma unroll
            for (int n = 0; n < 4; ++n) {
                float cx = acc[m][n][r] + bv[n];
                s += silu(cx) * w3v[n];
            }
            #pragma unroll
            for (int off = 1; off < 16; off <<= 1) s += __shfl_xor(s, off);
            if (li == 0) rsum[wc][wr*64 + m*16 + lg*4 + r] = s;
        }
    __syncthreads();
    float e = 0.f;
    if (t < 128) {
        int row = row0 + t;
        if (row < M) {
            float v = rsum[0][t] + rsum[1][t];
            int z = Z[row];
            e = scale[z] * v;
            if ((lin & 3) == 0) e += scale[z] * b3[0] + shift[z];
        }
    }
    #pragma unroll
    for (int off = 32; off > 0; off >>= 1) e += __shfl_down(e, off);
    if (lane == 0) red[w] = e;
    __syncthreads();
    if (t == 0) atomicAdd(out, red[0] + red[1] + red[2] + red[3]);
}

extern "C" void kernel_launch(void* const* d_in, const int* in_sizes, int n_in,
                              void* d_out, int out_size, void* d_ws, size_t ws_size,
                              hipStream_t stream)
{
    const float* R       = (const float*)d_in[0];
    const int*   Z       = (const int*)  d_in[1];
    const int*   idx     = (const int*)  d_in[2];
    const float* centers = (const float*)d_in[5];
    const float* width   = (const float*)d_in[6];
    const float* W1      = (const float*)d_in[7];
    const float* b1      = (const float*)d_in[8];
    const float* W2      = (const float*)d_in[9];
    const float* b2      = (const float*)d_in[10];
    const float* W3      = (const float*)d_in[11];
    const float* b3      = (const float*)d_in[12];
    const float* scale   = (const float*)d_in[13];
    const float* shift   = (const float*)d_in[14];

    int nAtoms = in_sizes[0] / 3;
    int nEdges = in_sizes[2] / 2;

    size_t m0m1_b = (size_t)nAtoms * 64 * sizeof(float);   // 25.6 MB
    size_t h1_b   = (size_t)nAtoms * HID * 2;              // 102.4 MB region (h1 fp8 uses half)
    size_t w1t_b  = (size_t)HID * K1P * 2;                 // 288 KB
    size_t w2t_b  = (size_t)HID * HID * 2;                 // 512 KB
    size_t w1f_b  = (size_t)HID * K1F * 2;                 // 160 KB
    size_t w2f8_b = (size_t)HID * HID;                     // 256 KB
    size_t feat_b = (size_t)nAtoms * K1F * 2;              // 32 MB
    if (ws_size < m0m1_b + h1_b + w1t_b + w2t_b) return;
    int useFeat = (ws_size >= m0m1_b + h1_b + w1t_b + w2t_b + w1f_b + w2f8_b + feat_b) ? 1 : 0;

    char* ws = (char*)d_ws;
    float* M0M1  = (float*)ws;
    char*  regB  = ws + m0m1_b;
    short* h1    = (short*)regB;                  // bf16 fallback
    unsigned char* h1f8 = (unsigned char*)regB;   // fp8 path
    short* W1t   = (short*)(ws + m0m1_b + h1_b);
    short* W2t   = W1t + (size_t)HID * K1P;
    short* W1f   = W2t + (size_t)HID * HID;
    unsigned char* W2f8 = (unsigned char*)(W1f + (size_t)HID * K1F);
    short* feat16 = (short*)(ws + m0m1_b + h1_b + w1t_b + w2t_b + w1f_b + w2f8_b);

    int nb = (nAtoms + 1023) / 1024;
    size_t sorted_b = (size_t)nEdges * sizeof(float4);     // 25.6 MB
    float4* sorted = (float4*)regB;
    int* counts   = (int*)(regB + sorted_b);
    int* starts   = counts + nAtoms;
    int* cursor   = starts + nAtoms + 1;
    int* blockSum = cursor + nAtoms;
    int* blockOff = blockSum + nb;
    if (sorted_b + (size_t)(3 * nAtoms + 1 + 2 * nb) * sizeof(int) > h1_b) return;

    float* out = (float*)d_out;

    hipMemsetAsync(counts, 0, (size_t)nAtoms * sizeof(int), stream);
    hipMemsetAsync(out, 0, sizeof(float), stream);

    convW_kernel<<<dim3(2, K1P), 256, 0, stream>>>(W1, W1t, 272, K1P, HID);
    if (useFeat) {
        convW1f_kernel<<<dim3(2, K1F), 256, 0, stream>>>(W1, W1f, HID);
        convW2f8_kernel<<<dim3(2, HID), 256, 0, stream>>>(W2, W2f8, HID);
    } else {
        convW_kernel<<<dim3(2, HID), 256, 0, stream>>>(W2, W2t, HID, HID, HID);
    }

    int vec4 = ((nEdges & 3) == 0) ? 1 : 0;
    int hb = vec4 ? ((nEdges / 4) + 255) / 256 : (nEdges + 255) / 256;
    hist_kernel <<<hb, 256, 0, stream>>>(idx, counts, nEdges, vec4);
    scan1_kernel<<<nb, 1024, 0, stream>>>(counts, starts, blockSum, nAtoms);
    scan2_kernel<<<1, 1024, 0, stream>>>(blockSum, blockOff, starts, nb, nAtoms);
    scan3_kernel<<<nb, 1024, 0, stream>>>(starts, cursor, blockOff, nAtoms);
    scatter2_kernel<<<8 * NBG, 256, 0, stream>>>(R, idx, cursor, sorted, nEdges, nAtoms);
    accum_kernel<<<(nAtoms + 3) / 4, 256, 0, stream>>>(sorted, starts, centers, width,
                                                       M0M1, feat16, nAtoms, useFeat);

    int gb = (nAtoms + 127) / 128;   // 782 row-blocks
    int nwg = gb * 4;                // x4 col-blocks, col-fast in lin order
    if (useFeat) {
        gemm_feat<<<nwg, 256, 0, stream>>>(feat16, W1f, b1, h1f8, nAtoms, nwg);
        gemm2_fp8<<<nwg, 256, 0, stream>>>(h1f8, W2f8, b2, W3, b3, scale, shift, Z, out, nAtoms, nwg);
    } else {
        gemm1_mfma<<<nwg, 256, 0, stream>>>(M0M1, W1t, b1, h1, nAtoms, nwg);
        gemm2_mfma<<<nwg, 256, 0, stream>>>(h1, W2t, b2, W3, b3, scale, shift, Z, out, nAtoms, nwg);
    }
}

// Round 23
// 403.070 us; speedup vs baseline: 1.0245x; 1.0245x over previous
//
#include <hip/hip_runtime.h>
#include <hip/hip_bf16.h>
#include <cstdint>

#define HID 512
#define K1P 288   // unfolded feat K padded 272 -> 288 (fallback path)
#define K1F 160   // folded feat K: 16 + 136 upper-tri, padded 152 -> 160 (5 x BK32)
#define NBG 96    // scatter blocks per XCD group

typedef __attribute__((ext_vector_type(8))) short bf16x8;
typedef __attribute__((ext_vector_type(4))) float f32x4;
typedef __attribute__((ext_vector_type(4))) _Float16 h16x4;

__device__ __forceinline__ short f2bf(float x) {
    __hip_bfloat16 h = __float2bfloat16(x);
    return *(short*)&h;
}
__device__ __forceinline__ unsigned char f2fp8(float x) {
    int p = __builtin_amdgcn_cvt_pk_fp8_f32(x, x, 0, false);
    return (unsigned char)(p & 0xff);
}
__device__ __forceinline__ float silu(float x) {
    return x * (1.0f / (1.0f + __expf(-x)));
}
__device__ __forceinline__ void gl_lds16(const void* src, void* dst) {
    __builtin_amdgcn_global_load_lds(
        (const __attribute__((address_space(1))) void*)src,
        (__attribute__((address_space(3))) void*)dst, 16, 0, 0);
}
// bijective XCD swizzle (m204)
__device__ __forceinline__ int xcd_swz(int bid, int nwg) {
    int q = nwg >> 3, r = nwg & 7;
    int xcd = bid & 7, i = bid >> 3;
    int base = (xcd < r) ? xcd * (q + 1) : r * (q + 1) + (xcd - r) * q;
    return base + i;
}
// inverse upper-triangle index: g in [0,136) -> (a,b) with a<=b
__device__ __forceinline__ void tri_ab(int g, int& a, int& b) {
    int aa = 0, rem = g;
    while (rem >= 16 - aa) { rem -= 16 - aa; ++aa; }
    a = aa; b = aa + rem;
}

// ---------- 1) histogram (int4-vectorized) ----------
__global__ __launch_bounds__(256) void hist_kernel(
    const int* __restrict__ idx, int* __restrict__ counts, int nEdges, int vec4)
{
    int q = blockIdx.x * 256 + threadIdx.x;
    if (vec4) {
        int nq = nEdges >> 2;
        if (q < nq) {
            int4 v = ((const int4*)idx)[q];
            atomicAdd(&counts[v.x], 1); atomicAdd(&counts[v.y], 1);
            atomicAdd(&counts[v.z], 1); atomicAdd(&counts[v.w], 1);
        }
    } else {
        if (q < nEdges) atomicAdd(&counts[idx[q]], 1);
    }
}

// ---------- 2) scan, pass 1 ----------
__global__ __launch_bounds__(1024) void scan1_kernel(
    const int* __restrict__ counts, int* __restrict__ starts,
    int* __restrict__ blockSum, int n)
{
    __shared__ int wsum[16];
    int t = threadIdx.x, lane = t & 63, wid = t >> 6;
    int i = blockIdx.x * 1024 + t;
    int v = (i < n) ? counts[i] : 0;
    int incl = v;
    #pragma unroll
    for (int off = 1; off < 64; off <<= 1) {
        int u = __shfl_up(incl, off);
        if (lane >= off) incl += u;
    }
    if (lane == 63) wsum[wid] = incl;
    __syncthreads();
    if (t < 16) {
        int s = wsum[t];
        #pragma unroll
        for (int off = 1; off < 16; off <<= 1) {
            int u = __shfl_up(s, off);
            if (t >= off) s += u;
        }
        wsum[t] = s;
    }
    __syncthreads();
    int woff = (wid == 0) ? 0 : wsum[wid - 1];
    if (i < n) starts[i] = woff + incl - v;
    if (t == 0) blockSum[blockIdx.x] = wsum[15];
}

// ---------- 2b) scan block sums ----------
__global__ __launch_bounds__(1024) void scan2_kernel(
    const int* __restrict__ blockSum, int* __restrict__ blockOff,
    int* __restrict__ starts, int nb, int n)
{
    __shared__ int arr[1024];
    int t = threadIdx.x;
    int v = (t < nb) ? blockSum[t] : 0;
    arr[t] = v;
    __syncthreads();
    #pragma unroll
    for (int off = 1; off < 1024; off <<= 1) {
        int x = (t >= off) ? arr[t - off] : 0;
        __syncthreads();
        arr[t] += x;
        __syncthreads();
    }
    if (t < nb) blockOff[t] = arr[t] - v;
    if (t == 0) starts[n] = arr[nb - 1];
}

// ---------- 2c) add offsets ----------
__global__ __launch_bounds__(1024) void scan3_kernel(
    int* __restrict__ starts, int* __restrict__ cursor,
    const int* __restrict__ blockOff, int n)
{
    int i = blockIdx.x * 1024 + threadIdx.x;
    if (i < n) {
        int s = starts[i] + blockOff[blockIdx.x];
        starts[i] = s;
        cursor[i] = s;
    }
}

// ---------- 3) XCD-partitioned scatter, fp16x4 payload (8B) ----------
__global__ __launch_bounds__(256) void scatter2_kernel(
    const float* __restrict__ R, const int* __restrict__ idx,
    int* __restrict__ cursor, h16x4* __restrict__ sorted, int nEdges, int nAtoms)
{
    int g  = blockIdx.x & 7;
    int gb = blockIdx.x >> 3;
    int per = (nAtoms + 7) >> 3;
    int lo = g * per;
    int hi = lo + per; if (hi > nAtoms) hi = nAtoms;

    auto emit = [&](int i, int j) {
        if (i < lo || i >= hi) return;
        float rix = R[3*(size_t)i], riy = R[3*(size_t)i+1], riz = R[3*(size_t)i+2];
        float rjx = R[3*(size_t)j], rjy = R[3*(size_t)j+1], rjz = R[3*(size_t)j+2];
        float dx = rjx - rix, dy = rjy - riy, dz = rjz - riz;
        float r = sqrtf(dx*dx + dy*dy + dz*dz);
        float inv = 1.0f / (r + 1e-8f);
        int pos = atomicAdd(&cursor[i], 1);
        h16x4 v = { (_Float16)r, (_Float16)(dx*inv), (_Float16)(dy*inv), (_Float16)(dz*inv) };
        sorted[pos] = v;
    };

    if ((nEdges & 3) == 0) {
        int nq = nEdges >> 2;
        const int4* i4p = (const int4*)idx;
        const int4* j4p = (const int4*)(idx + nEdges);
        for (int q = gb * 256 + threadIdx.x; q < nq; q += NBG * 256) {
            int4 iv = i4p[q], jv = j4p[q];
            emit(iv.x, jv.x); emit(iv.y, jv.y);
            emit(iv.z, jv.z); emit(iv.w, jv.w);
        }
    } else {
        for (int e = gb * 256 + threadIdx.x; e < nEdges; e += NBG * 256)
            emit(idx[e], idx[nEdges + e]);
    }
}

// ---------- 4) segmented reduce (fp16x4 payload) + fused folded-feat ----------
__global__ __launch_bounds__(256) void accum_kernel(
    const h16x4* __restrict__ sorted, const int* __restrict__ starts,
    const float* __restrict__ centers, const float* __restrict__ width,
    float* __restrict__ M0M1, short* __restrict__ feat16,
    int nAtoms, int useFeat)
{
    __shared__ float sm[4][64];
    int wv = threadIdx.x >> 6, lane = threadIdx.x & 63;
    int atom = blockIdx.x * 4 + wv;
    if (atom >= nAtoms) return;
    int s = starts[atom], e = starts[atom + 1];
    int k = lane >> 2, c = lane & 3;
    float ck = centers[k];
    float w = width[0];
    float inv2w2 = 1.0f / (2.0f * w * w);
    float acc = 0.0f;
    auto term = [&](h16x4 v) {
        float r = (float)v[0];
        float diff = r - ck;
        float b = __expf(-diff * diff * inv2w2);
        float comp = (c == 0) ? 1.0f : ((c == 1) ? (float)v[1] : ((c == 2) ? (float)v[2] : (float)v[3]));
        return b * comp;
    };
    int p = s;
    for (; p + 3 < e; p += 4) {
        h16x4 v0 = sorted[p];
        h16x4 v1 = sorted[p + 1];
        h16x4 v2 = sorted[p + 2];
        h16x4 v3 = sorted[p + 3];
        acc += term(v0); acc += term(v1); acc += term(v2); acc += term(v3);
    }
    for (; p < e; ++p) acc += term(sorted[p]);

    if (!useFeat) {
        M0M1[(size_t)atom * 64 + lane] = acc;
        return;
    }
    sm[wv][lane] = acc;
    asm volatile("s_waitcnt lgkmcnt(0)" ::: "memory");
    short* frow = feat16 + (size_t)atom * K1F;
    #pragma unroll
    for (int q = 0; q < 3; ++q) {
        int idx5 = q * 64 + lane;
        if (idx5 >= K1F) break;
        float val;
        if (idx5 < 16) {
            val = sm[wv][4 * idx5];
        } else if (idx5 < 152) {
            int a, b;
            tri_ab(idx5 - 16, a, b);
            val = sm[wv][4*a+1] * sm[wv][4*b+1]
                + sm[wv][4*a+2] * sm[wv][4*b+2]
                + sm[wv][4*a+3] * sm[wv][4*b+3];
        } else {
            val = 0.0f;
        }
        frow[idx5] = f2bf(val);
    }
}

// ---------- W -> bf16 transposed (fallback W1t + W2t) ----------
__global__ __launch_bounds__(256) void convW_kernel(
    const float* __restrict__ W, short* __restrict__ Wt, int K, int Kpad, int N)
{
    int n = blockIdx.x * 256 + threadIdx.x;
    int k = blockIdx.y;
    if (n >= N) return;
    float v = (k < K) ? W[(size_t)k * N + n] : 0.0f;
    Wt[(size_t)n * Kpad + k] = f2bf(v);
}

// ---------- W1 -> folded bf16 transposed W1f[n][160] ----------
__global__ __launch_bounds__(256) void convW1f_kernel(
    const float* __restrict__ W, short* __restrict__ Wf, int N)
{
    int n = blockIdx.x * 256 + threadIdx.x;
    int k = blockIdx.y;
    if (n >= N) return;
    float v;
    if (k < 16) {
        v = W[(size_t)k * N + n];
    } else if (k < 152) {
        int a, b;
        tri_ab(k - 16, a, b);
        v = W[(size_t)(16 + a*16 + b) * N + n];
        if (b > a) v += W[(size_t)(16 + b*16 + a) * N + n];
    } else {
        v = 0.0f;
    }
    Wf[(size_t)n * K1F + k] = f2bf(v);
}

// ---------- W2 -> fp8 e4m3 transposed, pre-scaled x16: W2f8[n][512] ----------
__global__ __launch_bounds__(256) void convW2f8_kernel(
    const float* __restrict__ W, unsigned char* __restrict__ Wf, int N)
{
    int n = blockIdx.x * 256 + threadIdx.x;
    int k = blockIdx.y;
    if (n >= N) return;
    Wf[(size_t)n * HID + k] = f2fp8(W[(size_t)k * N + n] * 16.0f);
}

// ============ GEMM1 fallback (R10 verbatim, bf16 h1) ============
__global__ __launch_bounds__(256, 2) void gemm1_mfma(
    const float* __restrict__ M0M1, const short* __restrict__ W1t,
    const float* __restrict__ bias, short* __restrict__ C, int M, int nwg)
{
    __shared__ float MsT[64][128];
    __shared__ short Asl[2][4096];
    __shared__ short Bsl[4][4096];
    int t = threadIdx.x;
    int w = t >> 6, lane = t & 63;
    int wr = w >> 1, wc = w & 1;
    int li = lane & 15, lg = lane >> 4;
    int lin = xcd_swz(blockIdx.x, nwg);
    int row0 = (lin >> 2) * 128;
    int col0 = (lin & 3) * 128;

    {
        int mrow = t >> 1, mo = (t & 1) * 32;
        int gm = row0 + mrow; if (gm > M - 1) gm = M - 1;
        const float4* src = (const float4*)(M0M1 + (size_t)gm * 64 + mo);
        #pragma unroll
        for (int q = 0; q < 8; ++q) {
            float4 v = src[q];
            int c0 = mo + q * 4;
            MsT[c0+0][mrow] = v.x; MsT[c0+1][mrow] = v.y;
            MsT[c0+2][mrow] = v.z; MsT[c0+3][mrow] = v.w;
        }
    }
    __syncthreads();

    auto stageA = [&](int kt, int buf) {
        #pragma unroll
        for (int p = 0; p < 2; ++p) {
            int cell = p * 256 + t;
            int k8 = cell >> 7, row = cell & 127;
            int kbase = kt * 32 + k8 * 8;
            bf16x8 v;
            if (kbase < 16) {
                #pragma unroll
                for (int j = 0; j < 8; ++j) v[j] = f2bf(MsT[4*(kbase+j)][row]);
            } else if (kbase < 272) {
                int g = kbase - 16, a = g >> 4, b0 = g & 15;
                float ax = MsT[4*a+1][row], ay = MsT[4*a+2][row], az = MsT[4*a+3][row];
                #pragma unroll
                for (int j = 0; j < 8; ++j) {
                    int b = b0 + j;
                    v[j] = f2bf(ax*MsT[4*b+1][row] + ay*MsT[4*b+2][row] + az*MsT[4*b+3][row]);
                }
            } else {
                #pragma unroll
                for (int j = 0; j < 8; ++j) v[j] = 0;
            }
            *(bf16x8*)&Asl[buf][cell * 8] = v;
        }
    };
    auto stageB = [&](int kt, int buf) {
        #pragma unroll
        for (int p = 0; p < 2; ++p) {
            int cell = p * 256 + t;
            int k8 = cell >> 7, col = cell & 127;
            const short* src = W1t + (size_t)(col0 + col) * K1P + kt*32 + k8*8;
            gl_lds16(src, &Bsl[buf][(p * 256 + w * 64) * 8]);
        }
    };

    f32x4 acc[4][4] = {};
    const int NS = K1P / 32;
    stageA(0, 0);
    stageB(0, 0); stageB(1, 1); stageB(2, 2);

    #pragma unroll
    for (int s = 0; s < NS; ++s) {
        if (s <= NS - 3)      asm volatile("s_waitcnt vmcnt(4) lgkmcnt(0)\n\ts_barrier" ::: "memory");
        else if (s == NS - 2) asm volatile("s_waitcnt vmcnt(2) lgkmcnt(0)\n\ts_barrier" ::: "memory");
        else                  asm volatile("s_waitcnt vmcnt(0) lgkmcnt(0)\n\ts_barrier" ::: "memory");
        if (s + 3 < NS) stageB(s + 3, (s + 3) & 3);
        bf16x8 af[4], bfr[4];
        #pragma unroll
        for (int m = 0; m < 4; ++m)
            af[m] = *(const bf16x8*)&Asl[s & 1][(lg*128 + wr*64 + m*16 + li) * 8];
        #pragma unroll
        for (int n = 0; n < 4; ++n)
            bfr[n] = *(const bf16x8*)&Bsl[s & 3][(lg*128 + wc*64 + n*16 + li) * 8];
        if (s + 1 < NS) stageA(s + 1, (s + 1) & 1);
        __builtin_amdgcn_s_setprio(1);
        #pragma unroll
        for (int m = 0; m < 4; ++m)
            #pragma unroll
            for (int n = 0; n < 4; ++n)
                acc[m][n] = __builtin_amdgcn_mfma_f32_16x16x32_bf16(af[m], bfr[n], acc[m][n], 0, 0, 0);
        __builtin_amdgcn_s_setprio(0);
    }

    float bv[4];
    #pragma unroll
    for (int n = 0; n < 4; ++n) bv[n] = bias[col0 + wc*64 + n*16 + li];
    #pragma unroll
    for (int m = 0; m < 4; ++m)
        #pragma unroll
        for (int r = 0; r < 4; ++r) {
            int row = row0 + wr*64 + m*16 + lg*4 + r;
            if (row >= M) continue;
            size_t base = (size_t)row * HID + col0 + wc*64 + li;
            #pragma unroll
            for (int n = 0; n < 4; ++n) {
                float cx = acc[m][n][r] + bv[n];
                C[base + n*16] = f2bf(silu(cx));
            }
        }
}

// ============ GEMM1 folded-feat (R18 struct) -> h1 in fp8 e4m3 ============
__global__ __launch_bounds__(256, 3) void gemm_feat(
    const short* __restrict__ F, const short* __restrict__ W1f,
    const float* __restrict__ bias, unsigned char* __restrict__ C, int M, int nwg)
{
    __shared__ short Asl[3][4096];
    __shared__ short Bsl[3][4096];
    int t = threadIdx.x;
    int w = t >> 6, lane = t & 63;
    int wr = w >> 1, wc = w & 1;
    int li = lane & 15, lg = lane >> 4;
    int lin = xcd_swz(blockIdx.x, nwg);
    int row0 = (lin >> 2) * 128;
    int col0 = (lin & 3) * 128;

    int rr = t & 127, k8h = t >> 7;
    int grA = row0 + rr; if (grA > M - 1) grA = M - 1;
    const short* aSrc0 = F + (size_t)grA * K1F + k8h * 8;
    const short* aSrc1 = aSrc0 + 16;
    const short* bSrc0 = W1f + (size_t)(col0 + rr) * K1F + k8h * 8;
    const short* bSrc1 = bSrc0 + 16;

    auto stage = [&](int kt, int buf) {
        gl_lds16(aSrc0 + kt * 32, &Asl[buf][(w * 64) * 8]);
        gl_lds16(aSrc1 + kt * 32, &Asl[buf][(256 + w * 64) * 8]);
        gl_lds16(bSrc0 + kt * 32, &Bsl[buf][(w * 64) * 8]);
        gl_lds16(bSrc1 + kt * 32, &Bsl[buf][(256 + w * 64) * 8]);
    };

    f32x4 acc[4][4] = {};
    const int NS = K1F / 32;
    stage(0, 0); stage(1, 1);

    #pragma unroll
    for (int s = 0; s < NS; ++s) {
        if (s < NS - 1) asm volatile("s_waitcnt vmcnt(4)\n\ts_barrier" ::: "memory");
        else            asm volatile("s_waitcnt vmcnt(0)\n\ts_barrier" ::: "memory");
        if (s + 2 < NS) stage(s + 2, (s + 2) % 3);
        bf16x8 af[4], bfr[4];
        #pragma unroll
        for (int m = 0; m < 4; ++m)
            af[m] = *(const bf16x8*)&Asl[s % 3][(lg*128 + wr*64 + m*16 + li) * 8];
        #pragma unroll
        for (int n = 0; n < 4; ++n)
            bfr[n] = *(const bf16x8*)&Bsl[s % 3][(lg*128 + wc*64 + n*16 + li) * 8];
        __builtin_amdgcn_s_setprio(1);
        #pragma unroll
        for (int m = 0; m < 4; ++m)
            #pragma unroll
            for (int n = 0; n < 4; ++n)
                acc[m][n] = __builtin_amdgcn_mfma_f32_16x16x32_bf16(af[m], bfr[n], acc[m][n], 0, 0, 0);
        __builtin_amdgcn_s_setprio(0);
    }

    float bv[4];
    #pragma unroll
    for (int n = 0; n < 4; ++n) bv[n] = bias[col0 + wc*64 + n*16 + li];
    #pragma unroll
    for (int m = 0; m < 4; ++m)
        #pragma unroll
        for (int r = 0; r < 4; ++r) {
            int row = row0 + wr*64 + m*16 + lg*4 + r;
            if (row >= M) continue;
            size_t base = (size_t)row * HID + col0 + wc*64 + li;
            #pragma unroll
            for (int n = 0; n < 4; ++n) {
                float cx = acc[m][n][r] + bv[n];
                C[base + n*16] = f2fp8(silu(cx));
            }
        }
}

// ============ GEMM2 fp8 (R21 verbatim): 128x128, BK=32, 3-buf/1-ahead ============
__global__ __launch_bounds__(256, 3) void gemm2_fp8(
    const unsigned char* __restrict__ A, const unsigned char* __restrict__ W2f,
    const float* __restrict__ bias, const float* __restrict__ W3,
    const float* __restrict__ b3, const float* __restrict__ scale,
    const float* __restrict__ shift, const int* __restrict__ Z,
    float* __restrict__ out, int M, int nwg)
{
    __shared__ __align__(16) unsigned char Asl[3][4096];
    __shared__ __align__(16) unsigned char Bsl[3][4096];
    __shared__ float rsum[2][128];
    __shared__ float red[4];
    int t = threadIdx.x;
    int w = t >> 6, lane = t & 63;
    int wr = w >> 1, wc = w & 1;
    int li = lane & 15, lg = lane >> 4;
    int lin = xcd_swz(blockIdx.x, nwg);
    int row0 = (lin >> 2) * 128;
    int col0 = (lin & 3) * 128;

    int rr = t & 127, k16 = t >> 7;
    int grA = row0 + rr; if (grA > M - 1) grA = M - 1;
    const unsigned char* aSrc = A + (size_t)grA * HID + k16 * 16;
    const unsigned char* bSrc = W2f + (size_t)(col0 + rr) * HID + k16 * 16;

    auto stage = [&](int kt, int buf) {
        gl_lds16(aSrc + kt * 32, &Asl[buf][w * 1024]);
        gl_lds16(bSrc + kt * 32, &Bsl[buf][w * 1024]);
    };

    f32x4 acc[4][4] = {};
    const int NS = HID / 32;   // 16
    stage(0, 0); stage(1, 1);

    for (int s = 0; s < NS; ++s) {
        if (s < NS - 1) asm volatile("s_waitcnt vmcnt(2)\n\ts_barrier" ::: "memory");
        else            asm volatile("s_waitcnt vmcnt(0)\n\ts_barrier" ::: "memory");
        if (s + 2 < NS) stage(s + 2, (s + 2) % 3);
        long af[4], bfr[4];
        const unsigned char* Ab = &Asl[s % 3][(lg >> 1) * 2048 + (lg & 1) * 8 + (wr*64 + li) * 16];
        const unsigned char* Bb = &Bsl[s % 3][(lg >> 1) * 2048 + (lg & 1) * 8 + (wc*64 + li) * 16];
        #pragma unroll
        for (int m = 0; m < 4; ++m) af[m] = *(const long*)(Ab + m * 256);
        #pragma unroll
        for (int n = 0; n < 4; ++n) bfr[n] = *(const long*)(Bb + n * 256);
        __builtin_amdgcn_s_setprio(1);
        #pragma unroll
        for (int m = 0; m < 4; ++m)
            #pragma unroll
            for (int n = 0; n < 4; ++n)
                acc[m][n] = __builtin_amdgcn_mfma_f32_16x16x32_fp8_fp8(af[m], bfr[n], acc[m][n], 0, 0, 0);
        __builtin_amdgcn_s_setprio(0);
    }

    float bv[4], w3v[4];
    #pragma unroll
    for (int n = 0; n < 4; ++n) {
        int col = col0 + wc*64 + n*16 + li;
        bv[n]  = bias[col];
        w3v[n] = W3[col];
    }
    #pragma unroll
    for (int m = 0; m < 4; ++m)
        #pragma unroll
        for (int r = 0; r < 4; ++r) {
            float s = 0.f;
            #pragma unroll
            for (int n = 0; n < 4; ++n) {
                float cx = acc[m][n][r] * 0.0625f + bv[n];   // undo W2 x16 pre-scale
                s += silu(cx) * w3v[n];
            }
            #pragma unroll
            for (int off = 1; off < 16; off <<= 1) s += __shfl_xor(s, off);
            if (li == 0) rsum[wc][wr*64 + m*16 + lg*4 + r] = s;
        }
    __syncthreads();
    float e = 0.f;
    if (t < 128) {
        int row = row0 + t;
        if (row < M) {
            float v = rsum[0][t] + rsum[1][t];
            int z = Z[row];
            e = scale[z] * v;
            if ((lin & 3) == 0) e += scale[z] * b3[0] + shift[z];
        }
    }
    #pragma unroll
    for (int off = 32; off > 0; off >>= 1) e += __shfl_down(e, off);
    if (lane == 0) red[w] = e;
    __syncthreads();
    if (t == 0) atomicAdd(out, red[0] + red[1] + red[2] + red[3]);
}

// ============ GEMM2 bf16 fallback (R16 verbatim) ============
__global__ __launch_bounds__(256, 3) void gemm2_mfma(
    const short* __restrict__ A, const short* __restrict__ W2t,
    const float* __restrict__ bias, const float* __restrict__ W3,
    const float* __restrict__ b3, const float* __restrict__ scale,
    const float* __restrict__ shift, const int* __restrict__ Z,
    float* __restrict__ out, int M, int nwg)
{
    __shared__ short Asl[3][4096];
    __shared__ short Bsl[3][4096];
    __shared__ float rsum[2][128];
    __shared__ float red[4];
    int t = threadIdx.x;
    int w = t >> 6, lane = t & 63;
    int wr = w >> 1, wc = w & 1;
    int li = lane & 15, lg = lane >> 4;
    int lin = xcd_swz(blockIdx.x, nwg);
    int row0 = (lin >> 2) * 128;
    int col0 = (lin & 3) * 128;

    int rr = t & 127, k8h = t >> 7;
    int grA = row0 + rr; if (grA > M - 1) grA = M - 1;
    const short* aSrc0 = A + (size_t)grA * HID + k8h * 8;
    const short* aSrc1 = aSrc0 + 16;
    const short* bSrc0 = W2t + (size_t)(col0 + rr) * HID + k8h * 8;
    const short* bSrc1 = bSrc0 + 16;

    auto stage = [&](int kt, int buf) {
        gl_lds16(aSrc0 + kt * 32, &Asl[buf][(w * 64) * 8]);
        gl_lds16(aSrc1 + kt * 32, &Asl[buf][(256 + w * 64) * 8]);
        gl_lds16(bSrc0 + kt * 32, &Bsl[buf][(w * 64) * 8]);
        gl_lds16(bSrc1 + kt * 32, &Bsl[buf][(256 + w * 64) * 8]);
    };

    f32x4 acc[4][4] = {};
    const int NS = HID / 32;
    stage(0, 0); stage(1, 1);

    for (int s = 0; s < NS; ++s) {
        if (s < NS - 1) asm volatile("s_waitcnt vmcnt(4)\n\ts_barrier" ::: "memory");
        else            asm volatile("s_waitcnt vmcnt(0)\n\ts_barrier" ::: "memory");
        if (s + 2 < NS) stage(s + 2, (s + 2) % 3);
        bf16x8 af[4], bfr[4];
        #pragma unroll
        for (int m = 0; m < 4; ++m)
            af[m] = *(const bf16x8*)&Asl[s % 3][(lg*128 + wr*64 + m*16 + li) * 8];
        #pragma unroll
        for (int n = 0; n < 4; ++n)
            bfr[n] = *(const bf16x8*)&Bsl[s % 3][(lg*128 + wc*64 + n*16 + li) * 8];
        __builtin_amdgcn_s_setprio(1);
        #pragma unroll
        for (int m = 0; m < 4; ++m)
            #pragma unroll
            for (int n = 0; n < 4; ++n)
                acc[m][n] = __builtin_amdgcn_mfma_f32_16x16x32_bf16(af[m], bfr[n], acc[m][n], 0, 0, 0);
        __builtin_amdgcn_s_setprio(0);
    }

    float bv[4], w3v[4];
    #pragma unroll
    for (int n = 0; n < 4; ++n) {
        int col = col0 + wc*64 + n*16 + li;
        bv[n]  = bias[col];
        w3v[n] = W3[col];
    }
    #pragma unroll
    for (int m = 0; m < 4; ++m)
        #pragma unroll
        for (int r = 0; r < 4; ++r) {
            float s = 0.f;
            #pragma unroll
            for (int n = 0; n < 4; ++n) {
                float cx = acc[m][n][r] + bv[n];
                s += silu(cx) * w3v[n];
            }
            #pragma unroll
            for (int off = 1; off < 16; off <<= 1) s += __shfl_xor(s, off);
            if (li == 0) rsum[wc][wr*64 + m*16 + lg*4 + r] = s;
        }
    __syncthreads();
    float e = 0.f;
    if (t < 128) {
        int row = row0 + t;
        if (row < M) {
            float v = rsum[0][t] + rsum[1][t];
            int z = Z[row];
            e = scale[z] * v;
            if ((lin & 3) == 0) e += scale[z] * b3[0] + shift[z];
        }
    }
    #pragma unroll
    for (int off = 32; off > 0; off >>= 1) e += __shfl_down(e, off);
    if (lane == 0) red[w] = e;
    __syncthreads();
    if (t == 0) atomicAdd(out, red[0] + red[1] + red[2] + red[3]);
}

extern "C" void kernel_launch(void* const* d_in, const int* in_sizes, int n_in,
                              void* d_out, int out_size, void* d_ws, size_t ws_size,
                              hipStream_t stream)
{
    const float* R       = (const float*)d_in[0];
    const int*   Z       = (const int*)  d_in[1];
    const int*   idx     = (const int*)  d_in[2];
    const float* centers = (const float*)d_in[5];
    const float* width   = (const float*)d_in[6];
    const float* W1      = (const float*)d_in[7];
    const float* b1      = (const float*)d_in[8];
    const float* W2      = (const float*)d_in[9];
    const float* b2      = (const float*)d_in[10];
    const float* W3      = (const float*)d_in[11];
    const float* b3      = (const float*)d_in[12];
    const float* scale   = (const float*)d_in[13];
    const float* shift   = (const float*)d_in[14];

    int nAtoms = in_sizes[0] / 3;
    int nEdges = in_sizes[2] / 2;

    size_t m0m1_b = (size_t)nAtoms * 64 * sizeof(float);   // 25.6 MB
    size_t h1_b   = (size_t)nAtoms * HID * 2;              // 102.4 MB region
    size_t w1t_b  = (size_t)HID * K1P * 2;                 // 288 KB
    size_t w2t_b  = (size_t)HID * HID * 2;                 // 512 KB
    size_t w1f_b  = (size_t)HID * K1F * 2;                 // 160 KB
    size_t w2f8_b = (size_t)HID * HID;                     // 256 KB
    size_t feat_b = (size_t)nAtoms * K1F * 2;              // 32 MB
    if (ws_size < m0m1_b + h1_b + w1t_b + w2t_b) return;
    int useFeat = (ws_size >= m0m1_b + h1_b + w1t_b + w2t_b + w1f_b + w2f8_b + feat_b) ? 1 : 0;

    char* ws = (char*)d_ws;
    float* M0M1  = (float*)ws;
    char*  regB  = ws + m0m1_b;
    short* h1    = (short*)regB;                  // bf16 fallback
    unsigned char* h1f8 = (unsigned char*)regB;   // fp8 path
    short* W1t   = (short*)(ws + m0m1_b + h1_b);
    short* W2t   = W1t + (size_t)HID * K1P;
    short* W1f   = W2t + (size_t)HID * HID;
    unsigned char* W2f8 = (unsigned char*)(W1f + (size_t)HID * K1F);
    short* feat16 = (short*)(ws + m0m1_b + h1_b + w1t_b + w2t_b + w1f_b + w2f8_b);

    int nb = (nAtoms + 1023) / 1024;
    size_t sorted_b = (size_t)nEdges * sizeof(h16x4);      // 12.8 MB
    h16x4* sorted = (h16x4*)regB;
    int* counts   = (int*)(regB + sorted_b);
    int* starts   = counts + nAtoms;
    int* cursor   = starts + nAtoms + 1;
    int* blockSum = cursor + nAtoms;
    int* blockOff = blockSum + nb;
    if (sorted_b + (size_t)(3 * nAtoms + 1 + 2 * nb) * sizeof(int) > h1_b) return;

    float* out = (float*)d_out;

    hipMemsetAsync(counts, 0, (size_t)nAtoms * sizeof(int), stream);
    hipMemsetAsync(out, 0, sizeof(float), stream);

    convW_kernel<<<dim3(2, K1P), 256, 0, stream>>>(W1, W1t, 272, K1P, HID);
    if (useFeat) {
        convW1f_kernel<<<dim3(2, K1F), 256, 0, stream>>>(W1, W1f, HID);
        convW2f8_kernel<<<dim3(2, HID), 256, 0, stream>>>(W2, W2f8, HID);
    } else {
        convW_kernel<<<dim3(2, HID), 256, 0, stream>>>(W2, W2t, HID, HID, HID);
    }

    int vec4 = ((nEdges & 3) == 0) ? 1 : 0;
    int hb = vec4 ? ((nEdges / 4) + 255) / 256 : (nEdges + 255) / 256;
    hist_kernel <<<hb, 256, 0, stream>>>(idx, counts, nEdges, vec4);
    scan1_kernel<<<nb, 1024, 0, stream>>>(counts, starts, blockSum, nAtoms);
    scan2_kernel<<<1, 1024, 0, stream>>>(blockSum, blockOff, starts, nb, nAtoms);
    scan3_kernel<<<nb, 1024, 0, stream>>>(starts, cursor, blockOff, nAtoms);
    scatter2_kernel<<<8 * NBG, 256, 0, stream>>>(R, idx, cursor, sorted, nEdges, nAtoms);
    accum_kernel<<<(nAtoms + 3) / 4, 256, 0, stream>>>(sorted, starts, centers, width,
                                                       M0M1, feat16, nAtoms, useFeat);

    int gb = (nAtoms + 127) / 128;   // 782 row-blocks
    int nwg = gb * 4;                // x4 col-blocks, col-fast in lin order
    if (useFeat) {
        gemm_feat<<<nwg, 256, 0, stream>>>(feat16, W1f, b1, h1f8, nAtoms, nwg);
        gemm2_fp8<<<nwg, 256, 0, stream>>>(h1f8, W2f8, b2, W3, b3, scale, shift, Z, out, nAtoms, nwg);
    } else {
        gemm1_mfma<<<nwg, 256, 0, stream>>>(M0M1, W1t, b1, h1, nAtoms, nwg);
        gemm2_mfma<<<nwg, 256, 0, stream>>>(h1, W2t, b2, W3, b3, scale, shift, Z, out, nAtoms, nwg);
    }
}

// Round 24
// 391.061 us; speedup vs baseline: 1.0560x; 1.0307x over previous
//
#include <hip/hip_runtime.h>
#include <hip/hip_bf16.h>
#include <cstdint>

#define HID 512
#define K1P 288   // unfolded feat K padded 272 -> 288 (fallback path)
#define K1F 160   // folded feat K: 16 + 136 upper-tri, padded 152 -> 160 (5 x BK32)
#define NBG 96    // scatter blocks per XCD group

typedef __attribute__((ext_vector_type(8))) short bf16x8;
typedef __attribute__((ext_vector_type(4))) float f32x4;
typedef __attribute__((ext_vector_type(4))) _Float16 h16x4;

__device__ __forceinline__ short f2bf(float x) {
    __hip_bfloat16 h = __float2bfloat16(x);
    return *(short*)&h;
}
__device__ __forceinline__ unsigned char f2fp8(float x) {
    int p = __builtin_amdgcn_cvt_pk_fp8_f32(x, x, 0, false);
    return (unsigned char)(p & 0xff);
}
__device__ __forceinline__ float silu(float x) {
    return x * (1.0f / (1.0f + __expf(-x)));
}
__device__ __forceinline__ void gl_lds16(const void* src, void* dst) {
    __builtin_amdgcn_global_load_lds(
        (const __attribute__((address_space(1))) void*)src,
        (__attribute__((address_space(3))) void*)dst, 16, 0, 0);
}
// bijective XCD swizzle (m204)
__device__ __forceinline__ int xcd_swz(int bid, int nwg) {
    int q = nwg >> 3, r = nwg & 7;
    int xcd = bid & 7, i = bid >> 3;
    int base = (xcd < r) ? xcd * (q + 1) : r * (q + 1) + (xcd - r) * q;
    return base + i;
}
// inverse upper-triangle index: g in [0,136) -> (a,b) with a<=b
__device__ __forceinline__ void tri_ab(int g, int& a, int& b) {
    int aa = 0, rem = g;
    while (rem >= 16 - aa) { rem -= 16 - aa; ++aa; }
    a = aa; b = aa + rem;
}

// ---------- 1) histogram (int4-vectorized) ----------
__global__ __launch_bounds__(256) void hist_kernel(
    const int* __restrict__ idx, int* __restrict__ counts, int nEdges, int vec4)
{
    int q = blockIdx.x * 256 + threadIdx.x;
    if (vec4) {
        int nq = nEdges >> 2;
        if (q < nq) {
            int4 v = ((const int4*)idx)[q];
            atomicAdd(&counts[v.x], 1); atomicAdd(&counts[v.y], 1);
            atomicAdd(&counts[v.z], 1); atomicAdd(&counts[v.w], 1);
        }
    } else {
        if (q < nEdges) atomicAdd(&counts[idx[q]], 1);
    }
}

// ---------- 2) scan, pass 1 ----------
__global__ __launch_bounds__(1024) void scan1_kernel(
    const int* __restrict__ counts, int* __restrict__ starts,
    int* __restrict__ blockSum, int n)
{
    __shared__ int wsum[16];
    int t = threadIdx.x, lane = t & 63, wid = t >> 6;
    int i = blockIdx.x * 1024 + t;
    int v = (i < n) ? counts[i] : 0;
    int incl = v;
    #pragma unroll
    for (int off = 1; off < 64; off <<= 1) {
        int u = __shfl_up(incl, off);
        if (lane >= off) incl += u;
    }
    if (lane == 63) wsum[wid] = incl;
    __syncthreads();
    if (t < 16) {
        int s = wsum[t];
        #pragma unroll
        for (int off = 1; off < 16; off <<= 1) {
            int u = __shfl_up(s, off);
            if (t >= off) s += u;
        }
        wsum[t] = s;
    }
    __syncthreads();
    int woff = (wid == 0) ? 0 : wsum[wid - 1];
    if (i < n) starts[i] = woff + incl - v;
    if (t == 0) blockSum[blockIdx.x] = wsum[15];
}

// ---------- 2b) scan block sums ----------
__global__ __launch_bounds__(1024) void scan2_kernel(
    const int* __restrict__ blockSum, int* __restrict__ blockOff,
    int* __restrict__ starts, int nb, int n)
{
    __shared__ int arr[1024];
    int t = threadIdx.x;
    int v = (t < nb) ? blockSum[t] : 0;
    arr[t] = v;
    __syncthreads();
    #pragma unroll
    for (int off = 1; off < 1024; off <<= 1) {
        int x = (t >= off) ? arr[t - off] : 0;
        __syncthreads();
        arr[t] += x;
        __syncthreads();
    }
    if (t < nb) blockOff[t] = arr[t] - v;
    if (t == 0) starts[n] = arr[nb - 1];
}

// ---------- 2c) add offsets ----------
__global__ __launch_bounds__(1024) void scan3_kernel(
    int* __restrict__ starts, int* __restrict__ cursor,
    const int* __restrict__ blockOff, int n)
{
    int i = blockIdx.x * 1024 + threadIdx.x;
    if (i < n) {
        int s = starts[i] + blockOff[blockIdx.x];
        starts[i] = s;
        cursor[i] = s;
    }
}

// ---------- 3) XCD-partitioned scatter, fp16x4 payload (8B) ----------
__global__ __launch_bounds__(256) void scatter2_kernel(
    const float* __restrict__ R, const int* __restrict__ idx,
    int* __restrict__ cursor, h16x4* __restrict__ sorted, int nEdges, int nAtoms)
{
    int g  = blockIdx.x & 7;
    int gb = blockIdx.x >> 3;
    int per = (nAtoms + 7) >> 3;
    int lo = g * per;
    int hi = lo + per; if (hi > nAtoms) hi = nAtoms;

    auto emit = [&](int i, int j) {
        if (i < lo || i >= hi) return;
        float rix = R[3*(size_t)i], riy = R[3*(size_t)i+1], riz = R[3*(size_t)i+2];
        float rjx = R[3*(size_t)j], rjy = R[3*(size_t)j+1], rjz = R[3*(size_t)j+2];
        float dx = rjx - rix, dy = rjy - riy, dz = rjz - riz;
        float r = sqrtf(dx*dx + dy*dy + dz*dz);
        float inv = 1.0f / (r + 1e-8f);
        int pos = atomicAdd(&cursor[i], 1);
        h16x4 v = { (_Float16)r, (_Float16)(dx*inv), (_Float16)(dy*inv), (_Float16)(dz*inv) };
        sorted[pos] = v;
    };

    if ((nEdges & 3) == 0) {
        int nq = nEdges >> 2;
        const int4* i4p = (const int4*)idx;
        const int4* j4p = (const int4*)(idx + nEdges);
        for (int q = gb * 256 + threadIdx.x; q < nq; q += NBG * 256) {
            int4 iv = i4p[q], jv = j4p[q];
            emit(iv.x, jv.x); emit(iv.y, jv.y);
            emit(iv.z, jv.z); emit(iv.w, jv.w);
        }
    } else {
        for (int e = gb * 256 + threadIdx.x; e < nEdges; e += NBG * 256)
            emit(idx[e], idx[nEdges + e]);
    }
}

// ---------- 4) segmented reduce (fp16x4 payload) + fused folded-feat (fp8 out) ----------
__global__ __launch_bounds__(256) void accum_kernel(
    const h16x4* __restrict__ sorted, const int* __restrict__ starts,
    const float* __restrict__ centers, const float* __restrict__ width,
    float* __restrict__ M0M1, unsigned char* __restrict__ feat8,
    int nAtoms, int useFeat)
{
    __shared__ float sm[4][64];
    int wv = threadIdx.x >> 6, lane = threadIdx.x & 63;
    int atom = blockIdx.x * 4 + wv;
    if (atom >= nAtoms) return;
    int s = starts[atom], e = starts[atom + 1];
    int k = lane >> 2, c = lane & 3;
    float ck = centers[k];
    float w = width[0];
    float inv2w2 = 1.0f / (2.0f * w * w);
    float acc = 0.0f;
    auto term = [&](h16x4 v) {
        float r = (float)v[0];
        float diff = r - ck;
        float b = __expf(-diff * diff * inv2w2);
        float comp = (c == 0) ? 1.0f : ((c == 1) ? (float)v[1] : ((c == 2) ? (float)v[2] : (float)v[3]));
        return b * comp;
    };
    int p = s;
    for (; p + 3 < e; p += 4) {
        h16x4 v0 = sorted[p];
        h16x4 v1 = sorted[p + 1];
        h16x4 v2 = sorted[p + 2];
        h16x4 v3 = sorted[p + 3];
        acc += term(v0); acc += term(v1); acc += term(v2); acc += term(v3);
    }
    for (; p < e; ++p) acc += term(sorted[p]);

    if (!useFeat) {
        M0M1[(size_t)atom * 64 + lane] = acc;
        return;
    }
    sm[wv][lane] = acc;
    asm volatile("s_waitcnt lgkmcnt(0)" ::: "memory");
    unsigned char* frow = feat8 + (size_t)atom * K1F;
    #pragma unroll
    for (int q = 0; q < 3; ++q) {
        int idx5 = q * 64 + lane;
        if (idx5 >= K1F) break;
        float val;
        if (idx5 < 16) {
            val = sm[wv][4 * idx5];
        } else if (idx5 < 152) {
            int a, b;
            tri_ab(idx5 - 16, a, b);
            val = sm[wv][4*a+1] * sm[wv][4*b+1]
                + sm[wv][4*a+2] * sm[wv][4*b+2]
                + sm[wv][4*a+3] * sm[wv][4*b+3];
        } else {
            val = 0.0f;
        }
        frow[idx5] = f2fp8(val);
    }
}

// ---------- W -> bf16 transposed (fallback W1t + W2t) ----------
__global__ __launch_bounds__(256) void convW_kernel(
    const float* __restrict__ W, short* __restrict__ Wt, int K, int Kpad, int N)
{
    int n = blockIdx.x * 256 + threadIdx.x;
    int k = blockIdx.y;
    if (n >= N) return;
    float v = (k < K) ? W[(size_t)k * N + n] : 0.0f;
    Wt[(size_t)n * Kpad + k] = f2bf(v);
}

// ---------- W1 -> folded fp8 transposed, pre-scaled x16: W1f8[n][160] ----------
__global__ __launch_bounds__(256) void convW1f8_kernel(
    const float* __restrict__ W, unsigned char* __restrict__ Wf, int N)
{
    int n = blockIdx.x * 256 + threadIdx.x;
    int k = blockIdx.y;
    if (n >= N) return;
    float v;
    if (k < 16) {
        v = W[(size_t)k * N + n];
    } else if (k < 152) {
        int a, b;
        tri_ab(k - 16, a, b);
        v = W[(size_t)(16 + a*16 + b) * N + n];
        if (b > a) v += W[(size_t)(16 + b*16 + a) * N + n];
    } else {
        v = 0.0f;
    }
    Wf[(size_t)n * K1F + k] = f2fp8(v * 16.0f);
}

// ---------- W2 -> fp8 e4m3 transposed, pre-scaled x16: W2f8[n][512] ----------
__global__ __launch_bounds__(256) void convW2f8_kernel(
    const float* __restrict__ W, unsigned char* __restrict__ Wf, int N)
{
    int n = blockIdx.x * 256 + threadIdx.x;
    int k = blockIdx.y;
    if (n >= N) return;
    Wf[(size_t)n * HID + k] = f2fp8(W[(size_t)k * N + n] * 16.0f);
}

// ============ GEMM1 fallback (R10 verbatim, bf16 h1; unused in fp8 path) ============
__global__ __launch_bounds__(256, 2) void gemm1_mfma(
    const float* __restrict__ M0M1, const short* __restrict__ W1t,
    const float* __restrict__ bias, short* __restrict__ C, int M, int nwg)
{
    __shared__ float MsT[64][128];
    __shared__ short Asl[2][4096];
    __shared__ short Bsl[4][4096];
    int t = threadIdx.x;
    int w = t >> 6, lane = t & 63;
    int wr = w >> 1, wc = w & 1;
    int li = lane & 15, lg = lane >> 4;
    int lin = xcd_swz(blockIdx.x, nwg);
    int row0 = (lin >> 2) * 128;
    int col0 = (lin & 3) * 128;

    {
        int mrow = t >> 1, mo = (t & 1) * 32;
        int gm = row0 + mrow; if (gm > M - 1) gm = M - 1;
        const float4* src = (const float4*)(M0M1 + (size_t)gm * 64 + mo);
        #pragma unroll
        for (int q = 0; q < 8; ++q) {
            float4 v = src[q];
            int c0 = mo + q * 4;
            MsT[c0+0][mrow] = v.x; MsT[c0+1][mrow] = v.y;
            MsT[c0+2][mrow] = v.z; MsT[c0+3][mrow] = v.w;
        }
    }
    __syncthreads();

    auto stageA = [&](int kt, int buf) {
        #pragma unroll
        for (int p = 0; p < 2; ++p) {
            int cell = p * 256 + t;
            int k8 = cell >> 7, row = cell & 127;
            int kbase = kt * 32 + k8 * 8;
            bf16x8 v;
            if (kbase < 16) {
                #pragma unroll
                for (int j = 0; j < 8; ++j) v[j] = f2bf(MsT[4*(kbase+j)][row]);
            } else if (kbase < 272) {
                int g = kbase - 16, a = g >> 4, b0 = g & 15;
                float ax = MsT[4*a+1][row], ay = MsT[4*a+2][row], az = MsT[4*a+3][row];
                #pragma unroll
                for (int j = 0; j < 8; ++j) {
                    int b = b0 + j;
                    v[j] = f2bf(ax*MsT[4*b+1][row] + ay*MsT[4*b+2][row] + az*MsT[4*b+3][row]);
                }
            } else {
                #pragma unroll
                for (int j = 0; j < 8; ++j) v[j] = 0;
            }
            *(bf16x8*)&Asl[buf][cell * 8] = v;
        }
    };
    auto stageB = [&](int kt, int buf) {
        #pragma unroll
        for (int p = 0; p < 2; ++p) {
            int cell = p * 256 + t;
            int k8 = cell >> 7, col = cell & 127;
            const short* src = W1t + (size_t)(col0 + col) * K1P + kt*32 + k8*8;
            gl_lds16(src, &Bsl[buf][(p * 256 + w * 64) * 8]);
        }
    };

    f32x4 acc[4][4] = {};
    const int NS = K1P / 32;
    stageA(0, 0);
    stageB(0, 0); stageB(1, 1); stageB(2, 2);

    #pragma unroll
    for (int s = 0; s < NS; ++s) {
        if (s <= NS - 3)      asm volatile("s_waitcnt vmcnt(4) lgkmcnt(0)\n\ts_barrier" ::: "memory");
        else if (s == NS - 2) asm volatile("s_waitcnt vmcnt(2) lgkmcnt(0)\n\ts_barrier" ::: "memory");
        else                  asm volatile("s_waitcnt vmcnt(0) lgkmcnt(0)\n\ts_barrier" ::: "memory");
        if (s + 3 < NS) stageB(s + 3, (s + 3) & 3);
        bf16x8 af[4], bfr[4];
        #pragma unroll
        for (int m = 0; m < 4; ++m)
            af[m] = *(const bf16x8*)&Asl[s & 1][(lg*128 + wr*64 + m*16 + li) * 8];
        #pragma unroll
        for (int n = 0; n < 4; ++n)
            bfr[n] = *(const bf16x8*)&Bsl[s & 3][(lg*128 + wc*64 + n*16 + li) * 8];
        if (s + 1 < NS) stageA(s + 1, (s + 1) & 1);
        __builtin_amdgcn_s_setprio(1);
        #pragma unroll
        for (int m = 0; m < 4; ++m)
            #pragma unroll
            for (int n = 0; n < 4; ++n)
                acc[m][n] = __builtin_amdgcn_mfma_f32_16x16x32_bf16(af[m], bfr[n], acc[m][n], 0, 0, 0);
        __builtin_amdgcn_s_setprio(0);
    }

    float bv[4];
    #pragma unroll
    for (int n = 0; n < 4; ++n) bv[n] = bias[col0 + wc*64 + n*16 + li];
    #pragma unroll
    for (int m = 0; m < 4; ++m)
        #pragma unroll
        for (int r = 0; r < 4; ++r) {
            int row = row0 + wr*64 + m*16 + lg*4 + r;
            if (row >= M) continue;
            size_t base = (size_t)row * HID + col0 + wc*64 + li;
            #pragma unroll
            for (int n = 0; n < 4; ++n) {
                float cx = acc[m][n][r] + bv[n];
                C[base + n*16] = f2bf(silu(cx));
            }
        }
}

// ============ GEMM1 fp8 (gemm2_fp8 clone, NS=5): h1 = silu(feat8 @ W1f8/16 + b1) ============
__global__ __launch_bounds__(256, 3) void gemm_feat_fp8(
    const unsigned char* __restrict__ F, const unsigned char* __restrict__ W1f8,
    const float* __restrict__ bias, unsigned char* __restrict__ C, int M, int nwg)
{
    __shared__ __align__(16) unsigned char Asl[3][4096];
    __shared__ __align__(16) unsigned char Bsl[3][4096];
    int t = threadIdx.x;
    int w = t >> 6, lane = t & 63;
    int wr = w >> 1, wc = w & 1;
    int li = lane & 15, lg = lane >> 4;
    int lin = xcd_swz(blockIdx.x, nwg);
    int row0 = (lin >> 2) * 128;
    int col0 = (lin & 3) * 128;

    int rr = t & 127, k16 = t >> 7;
    int grA = row0 + rr; if (grA > M - 1) grA = M - 1;
    const unsigned char* aSrc = F + (size_t)grA * K1F + k16 * 16;
    const unsigned char* bSrc = W1f8 + (size_t)(col0 + rr) * K1F + k16 * 16;

    auto stage = [&](int kt, int buf) {
        gl_lds16(aSrc + kt * 32, &Asl[buf][w * 1024]);
        gl_lds16(bSrc + kt * 32, &Bsl[buf][w * 1024]);
    };

    f32x4 acc[4][4] = {};
    const int NS = K1F / 32;   // 5
    stage(0, 0); stage(1, 1);

    #pragma unroll
    for (int s = 0; s < NS; ++s) {
        if (s < NS - 1) asm volatile("s_waitcnt vmcnt(2)\n\ts_barrier" ::: "memory");
        else            asm volatile("s_waitcnt vmcnt(0)\n\ts_barrier" ::: "memory");
        if (s + 2 < NS) stage(s + 2, (s + 2) % 3);
        long af[4], bfr[4];
        const unsigned char* Ab = &Asl[s % 3][(lg >> 1) * 2048 + (lg & 1) * 8 + (wr*64 + li) * 16];
        const unsigned char* Bb = &Bsl[s % 3][(lg >> 1) * 2048 + (lg & 1) * 8 + (wc*64 + li) * 16];
        #pragma unroll
        for (int m = 0; m < 4; ++m) af[m] = *(const long*)(Ab + m * 256);
        #pragma unroll
        for (int n = 0; n < 4; ++n) bfr[n] = *(const long*)(Bb + n * 256);
        __builtin_amdgcn_s_setprio(1);
        #pragma unroll
        for (int m = 0; m < 4; ++m)
            #pragma unroll
            for (int n = 0; n < 4; ++n)
                acc[m][n] = __builtin_amdgcn_mfma_f32_16x16x32_fp8_fp8(af[m], bfr[n], acc[m][n], 0, 0, 0);
        __builtin_amdgcn_s_setprio(0);
    }

    float bv[4];
    #pragma unroll
    for (int n = 0; n < 4; ++n) bv[n] = bias[col0 + wc*64 + n*16 + li];
    #pragma unroll
    for (int m = 0; m < 4; ++m)
        #pragma unroll
        for (int r = 0; r < 4; ++r) {
            int row = row0 + wr*64 + m*16 + lg*4 + r;
            if (row >= M) continue;
            size_t base = (size_t)row * HID + col0 + wc*64 + li;
            #pragma unroll
            for (int n = 0; n < 4; ++n) {
                float cx = acc[m][n][r] * 0.0625f + bv[n];   // undo W1 x16 pre-scale
                C[base + n*16] = f2fp8(silu(cx));
            }
        }
}

// ============ GEMM2 fp8 (R21 verbatim): 128x128, BK=32, 3-buf/1-ahead ============
__global__ __launch_bounds__(256, 3) void gemm2_fp8(
    const unsigned char* __restrict__ A, const unsigned char* __restrict__ W2f,
    const float* __restrict__ bias, const float* __restrict__ W3,
    const float* __restrict__ b3, const float* __restrict__ scale,
    const float* __restrict__ shift, const int* __restrict__ Z,
    float* __restrict__ out, int M, int nwg)
{
    __shared__ __align__(16) unsigned char Asl[3][4096];
    __shared__ __align__(16) unsigned char Bsl[3][4096];
    __shared__ float rsum[2][128];
    __shared__ float red[4];
    int t = threadIdx.x;
    int w = t >> 6, lane = t & 63;
    int wr = w >> 1, wc = w & 1;
    int li = lane & 15, lg = lane >> 4;
    int lin = xcd_swz(blockIdx.x, nwg);
    int row0 = (lin >> 2) * 128;
    int col0 = (lin & 3) * 128;

    int rr = t & 127, k16 = t >> 7;
    int grA = row0 + rr; if (grA > M - 1) grA = M - 1;
    const unsigned char* aSrc = A + (size_t)grA * HID + k16 * 16;
    const unsigned char* bSrc = W2f + (size_t)(col0 + rr) * HID + k16 * 16;

    auto stage = [&](int kt, int buf) {
        gl_lds16(aSrc + kt * 32, &Asl[buf][w * 1024]);
        gl_lds16(bSrc + kt * 32, &Bsl[buf][w * 1024]);
    };

    f32x4 acc[4][4] = {};
    const int NS = HID / 32;   // 16
    stage(0, 0); stage(1, 1);

    for (int s = 0; s < NS; ++s) {
        if (s < NS - 1) asm volatile("s_waitcnt vmcnt(2)\n\ts_barrier" ::: "memory");
        else            asm volatile("s_waitcnt vmcnt(0)\n\ts_barrier" ::: "memory");
        if (s + 2 < NS) stage(s + 2, (s + 2) % 3);
        long af[4], bfr[4];
        const unsigned char* Ab = &Asl[s % 3][(lg >> 1) * 2048 + (lg & 1) * 8 + (wr*64 + li) * 16];
        const unsigned char* Bb = &Bsl[s % 3][(lg >> 1) * 2048 + (lg & 1) * 8 + (wc*64 + li) * 16];
        #pragma unroll
        for (int m = 0; m < 4; ++m) af[m] = *(const long*)(Ab + m * 256);
        #pragma unroll
        for (int n = 0; n < 4; ++n) bfr[n] = *(const long*)(Bb + n * 256);
        __builtin_amdgcn_s_setprio(1);
        #pragma unroll
        for (int m = 0; m < 4; ++m)
            #pragma unroll
            for (int n = 0; n < 4; ++n)
                acc[m][n] = __builtin_amdgcn_mfma_f32_16x16x32_fp8_fp8(af[m], bfr[n], acc[m][n], 0, 0, 0);
        __builtin_amdgcn_s_setprio(0);
    }

    float bv[4], w3v[4];
    #pragma unroll
    for (int n = 0; n < 4; ++n) {
        int col = col0 + wc*64 + n*16 + li;
        bv[n]  = bias[col];
        w3v[n] = W3[col];
    }
    #pragma unroll
    for (int m = 0; m < 4; ++m)
        #pragma unroll
        for (int r = 0; r < 4; ++r) {
            float s = 0.f;
            #pragma unroll
            for (int n = 0; n < 4; ++n) {
                float cx = acc[m][n][r] * 0.0625f + bv[n];   // undo W2 x16 pre-scale
                s += silu(cx) * w3v[n];
            }
            #pragma unroll
            for (int off = 1; off < 16; off <<= 1) s += __shfl_xor(s, off);
            if (li == 0) rsum[wc][wr*64 + m*16 + lg*4 + r] = s;
        }
    __syncthreads();
    float e = 0.f;
    if (t < 128) {
        int row = row0 + t;
        if (row < M) {
            float v = rsum[0][t] + rsum[1][t];
            int z = Z[row];
            e = scale[z] * v;
            if ((lin & 3) == 0) e += scale[z] * b3[0] + shift[z];
        }
    }
    #pragma unroll
    for (int off = 32; off > 0; off >>= 1) e += __shfl_down(e, off);
    if (lane == 0) red[w] = e;
    __syncthreads();
    if (t == 0) atomicAdd(out, red[0] + red[1] + red[2] + red[3]);
}

// ============ GEMM2 bf16 fallback (R16 verbatim) ============
__global__ __launch_bounds__(256, 3) void gemm2_mfma(
    const short* __restrict__ A, const short* __restrict__ W2t,
    const float* __restrict__ bias, const float* __restrict__ W3,
    const float* __restrict__ b3, const float* __restrict__ scale,
    const float* __restrict__ shift, const int* __restrict__ Z,
    float* __restrict__ out, int M, int nwg)
{
    __shared__ short Asl[3][4096];
    __shared__ short Bsl[3][4096];
    __shared__ float rsum[2][128];
    __shared__ float red[4];
    int t = threadIdx.x;
    int w = t >> 6, lane = t & 63;
    int wr = w >> 1, wc = w & 1;
    int li = lane & 15, lg = lane >> 4;
    int lin = xcd_swz(blockIdx.x, nwg);
    int row0 = (lin >> 2) * 128;
    int col0 = (lin & 3) * 128;

    int rr = t & 127, k8h = t >> 7;
    int grA = row0 + rr; if (grA > M - 1) grA = M - 1;
    const short* aSrc0 = A + (size_t)grA * HID + k8h * 8;
    const short* aSrc1 = aSrc0 + 16;
    const short* bSrc0 = W2t + (size_t)(col0 + rr) * HID + k8h * 8;
    const short* bSrc1 = bSrc0 + 16;

    auto stage = [&](int kt, int buf) {
        gl_lds16(aSrc0 + kt * 32, &Asl[buf][(w * 64) * 8]);
        gl_lds16(aSrc1 + kt * 32, &Asl[buf][(256 + w * 64) * 8]);
        gl_lds16(bSrc0 + kt * 32, &Bsl[buf][(w * 64) * 8]);
        gl_lds16(bSrc1 + kt * 32, &Bsl[buf][(256 + w * 64) * 8]);
    };

    f32x4 acc[4][4] = {};
    const int NS = HID / 32;
    stage(0, 0); stage(1, 1);

    for (int s = 0; s < NS; ++s) {
        if (s < NS - 1) asm volatile("s_waitcnt vmcnt(4)\n\ts_barrier" ::: "memory");
        else            asm volatile("s_waitcnt vmcnt(0)\n\ts_barrier" ::: "memory");
        if (s + 2 < NS) stage(s + 2, (s + 2) % 3);
        bf16x8 af[4], bfr[4];
        #pragma unroll
        for (int m = 0; m < 4; ++m)
            af[m] = *(const bf16x8*)&Asl[s % 3][(lg*128 + wr*64 + m*16 + li) * 8];
        #pragma unroll
        for (int n = 0; n < 4; ++n)
            bfr[n] = *(const bf16x8*)&Bsl[s % 3][(lg*128 + wc*64 + n*16 + li) * 8];
        __builtin_amdgcn_s_setprio(1);
        #pragma unroll
        for (int m = 0; m < 4; ++m)
            #pragma unroll
            for (int n = 0; n < 4; ++n)
                acc[m][n] = __builtin_amdgcn_mfma_f32_16x16x32_bf16(af[m], bfr[n], acc[m][n], 0, 0, 0);
        __builtin_amdgcn_s_setprio(0);
    }

    float bv[4], w3v[4];
    #pragma unroll
    for (int n = 0; n < 4; ++n) {
        int col = col0 + wc*64 + n*16 + li;
        bv[n]  = bias[col];
        w3v[n] = W3[col];
    }
    #pragma unroll
    for (int m = 0; m < 4; ++m)
        #pragma unroll
        for (int r = 0; r < 4; ++r) {
            float s = 0.f;
            #pragma unroll
            for (int n = 0; n < 4; ++n) {
                float cx = acc[m][n][r] + bv[n];
                s += silu(cx) * w3v[n];
            }
            #pragma unroll
            for (int off = 1; off < 16; off <<= 1) s += __shfl_xor(s, off);
            if (li == 0) rsum[wc][wr*64 + m*16 + lg*4 + r] = s;
        }
    __syncthreads();
    float e = 0.f;
    if (t < 128) {
        int row = row0 + t;
        if (row < M) {
            float v = rsum[0][t] + rsum[1][t];
            int z = Z[row];
            e = scale[z] * v;
            if ((lin & 3) == 0) e += scale[z] * b3[0] + shift[z];
        }
    }
    #pragma unroll
    for (int off = 32; off > 0; off >>= 1) e += __shfl_down(e, off);
    if (lane == 0) red[w] = e;
    __syncthreads();
    if (t == 0) atomicAdd(out, red[0] + red[1] + red[2] + red[3]);
}

extern "C" void kernel_launch(void* const* d_in, const int* in_sizes, int n_in,
                              void* d_out, int out_size, void* d_ws, size_t ws_size,
                              hipStream_t stream)
{
    const float* R       = (const float*)d_in[0];
    const int*   Z       = (const int*)  d_in[1];
    const int*   idx     = (const int*)  d_in[2];
    const float* centers = (const float*)d_in[5];
    const float* width   = (const float*)d_in[6];
    const float* W1      = (const float*)d_in[7];
    const float* b1      = (const float*)d_in[8];
    const float* W2      = (const float*)d_in[9];
    const float* b2      = (const float*)d_in[10];
    const float* W3      = (const float*)d_in[11];
    const float* b3      = (const float*)d_in[12];
    const float* scale   = (const float*)d_in[13];
    const float* shift   = (const float*)d_in[14];

    int nAtoms = in_sizes[0] / 3;
    int nEdges = in_sizes[2] / 2;

    size_t m0m1_b = (size_t)nAtoms * 64 * sizeof(float);   // 25.6 MB
    size_t h1_b   = (size_t)nAtoms * HID * 2;              // 102.4 MB region
    size_t w1t_b  = (size_t)HID * K1P * 2;                 // 288 KB
    size_t w2t_b  = (size_t)HID * HID * 2;                 // 512 KB
    size_t w1f_b  = (size_t)HID * K1F;                     // 80 KB (fp8)
    size_t w2f8_b = (size_t)HID * HID;                     // 256 KB
    size_t feat_b = (size_t)nAtoms * K1F;                  // 16 MB (fp8)
    if (ws_size < m0m1_b + h1_b + w1t_b + w2t_b) return;
    int useFeat = (ws_size >= m0m1_b + h1_b + w1t_b + w2t_b + w1f_b + w2f8_b + feat_b) ? 1 : 0;

    char* ws = (char*)d_ws;
    float* M0M1  = (float*)ws;
    char*  regB  = ws + m0m1_b;
    short* h1    = (short*)regB;                  // bf16 fallback
    unsigned char* h1f8 = (unsigned char*)regB;   // fp8 path
    short* W1t   = (short*)(ws + m0m1_b + h1_b);
    short* W2t   = W1t + (size_t)HID * K1P;
    unsigned char* W1f8 = (unsigned char*)(W2t + (size_t)HID * HID);
    unsigned char* W2f8 = W1f8 + (size_t)HID * K1F;
    unsigned char* feat8 = (unsigned char*)(ws + m0m1_b + h1_b + w1t_b + w2t_b + w1f_b + w2f8_b);

    int nb = (nAtoms + 1023) / 1024;
    size_t sorted_b = (size_t)nEdges * sizeof(h16x4);      // 12.8 MB
    h16x4* sorted = (h16x4*)regB;
    int* counts   = (int*)(regB + sorted_b);
    int* starts   = counts + nAtoms;
    int* cursor   = starts + nAtoms + 1;
    int* blockSum = cursor + nAtoms;
    int* blockOff = blockSum + nb;
    if (sorted_b + (size_t)(3 * nAtoms + 1 + 2 * nb) * sizeof(int) > h1_b) return;

    float* out = (float*)d_out;

    hipMemsetAsync(counts, 0, (size_t)nAtoms * sizeof(int), stream);
    hipMemsetAsync(out, 0, sizeof(float), stream);

    if (useFeat) {
        convW1f8_kernel<<<dim3(2, K1F), 256, 0, stream>>>(W1, W1f8, HID);
        convW2f8_kernel<<<dim3(2, HID), 256, 0, stream>>>(W2, W2f8, HID);
    } else {
        convW_kernel<<<dim3(2, K1P), 256, 0, stream>>>(W1, W1t, 272, K1P, HID);
        convW_kernel<<<dim3(2, HID), 256, 0, stream>>>(W2, W2t, HID, HID, HID);
    }

    int vec4 = ((nEdges & 3) == 0) ? 1 : 0;
    int hb = vec4 ? ((nEdges / 4) + 255) / 256 : (nEdges + 255) / 256;
    hist_kernel <<<hb, 256, 0, stream>>>(idx, counts, nEdges, vec4);
    scan1_kernel<<<nb, 1024, 0, stream>>>(counts, starts, blockSum, nAtoms);
    scan2_kernel<<<1, 1024, 0, stream>>>(blockSum, blockOff, starts, nb, nAtoms);
    scan3_kernel<<<nb, 1024, 0, stream>>>(starts, cursor, blockOff, nAtoms);
    scatter2_kernel<<<8 * NBG, 256, 0, stream>>>(R, idx, cursor, sorted, nEdges, nAtoms);
    accum_kernel<<<(nAtoms + 3) / 4, 256, 0, stream>>>(sorted, starts, centers, width,
                                                       M0M1, feat8, nAtoms, useFeat);

    int gb = (nAtoms + 127) / 128;   // 782 row-blocks
    int nwg = gb * 4;                // x4 col-blocks, col-fast in lin order
    if (useFeat) {
        gemm_feat_fp8<<<nwg, 256, 0, stream>>>(feat8, W1f8, b1, h1f8, nAtoms, nwg);
        gemm2_fp8<<<nwg, 256, 0, stream>>>(h1f8, W2f8, b2, W3, b3, scale, shift, Z, out, nAtoms, nwg);
    } else {
        gemm1_mfma<<<nwg, 256, 0, stream>>>(M0M1, W1t, b1, h1, nAtoms, nwg);
        gemm2_mfma<<<nwg, 256, 0, stream>>>(h1, W2t, b2, W3, b3, scale, shift, Z, out, nAtoms, nwg);
    }
}

// Round 25
// 382.562 us; speedup vs baseline: 1.0794x; 1.0222x over previous
//
#include <hip/hip_runtime.h>
#include <hip/hip_bf16.h>
#include <cstdint>

#define HID 512
#define K1P 288   // unfolded feat K padded 272 -> 288 (fallback path)
#define K1F 160   // folded feat K: 16 + 136 upper-tri, padded 152 -> 160 (5 x BK32)
#define NBG 96    // scatter blocks per XCD group

typedef __attribute__((ext_vector_type(8))) short bf16x8;
typedef __attribute__((ext_vector_type(4))) float f32x4;
typedef __attribute__((ext_vector_type(4))) _Float16 h16x4;

__device__ __forceinline__ short f2bf(float x) {
    __hip_bfloat16 h = __float2bfloat16(x);
    return *(short*)&h;
}
__device__ __forceinline__ unsigned char f2fp8(float x) {
    int p = __builtin_amdgcn_cvt_pk_fp8_f32(x, x, 0, false);
    return (unsigned char)(p & 0xff);
}
__device__ __forceinline__ float silu(float x) {
    return x * (1.0f / (1.0f + __expf(-x)));
}
__device__ __forceinline__ void gl_lds16(const void* src, void* dst) {
    __builtin_amdgcn_global_load_lds(
        (const __attribute__((address_space(1))) void*)src,
        (__attribute__((address_space(3))) void*)dst, 16, 0, 0);
}
// bijective XCD swizzle (m204)
__device__ __forceinline__ int xcd_swz(int bid, int nwg) {
    int q = nwg >> 3, r = nwg & 7;
    int xcd = bid & 7, i = bid >> 3;
    int base = (xcd < r) ? xcd * (q + 1) : r * (q + 1) + (xcd - r) * q;
    return base + i;
}
// inverse upper-triangle index: g in [0,136) -> (a,b) with a<=b
__device__ __forceinline__ void tri_ab(int g, int& a, int& b) {
    int aa = 0, rem = g;
    while (rem >= 16 - aa) { rem -= 16 - aa; ++aa; }
    a = aa; b = aa + rem;
}

// ---------- 1) histogram (int4-vectorized) ----------
__global__ __launch_bounds__(256) void hist_kernel(
    const int* __restrict__ idx, int* __restrict__ counts, int nEdges, int vec4)
{
    int q = blockIdx.x * 256 + threadIdx.x;
    if (vec4) {
        int nq = nEdges >> 2;
        if (q < nq) {
            int4 v = ((const int4*)idx)[q];
            atomicAdd(&counts[v.x], 1); atomicAdd(&counts[v.y], 1);
            atomicAdd(&counts[v.z], 1); atomicAdd(&counts[v.w], 1);
        }
    } else {
        if (q < nEdges) atomicAdd(&counts[idx[q]], 1);
    }
}

// ---------- 2) scan, pass 1 ----------
__global__ __launch_bounds__(1024) void scan1_kernel(
    const int* __restrict__ counts, int* __restrict__ starts,
    int* __restrict__ blockSum, int n)
{
    __shared__ int wsum[16];
    int t = threadIdx.x, lane = t & 63, wid = t >> 6;
    int i = blockIdx.x * 1024 + t;
    int v = (i < n) ? counts[i] : 0;
    int incl = v;
    #pragma unroll
    for (int off = 1; off < 64; off <<= 1) {
        int u = __shfl_up(incl, off);
        if (lane >= off) incl += u;
    }
    if (lane == 63) wsum[wid] = incl;
    __syncthreads();
    if (t < 16) {
        int s = wsum[t];
        #pragma unroll
        for (int off = 1; off < 16; off <<= 1) {
            int u = __shfl_up(s, off);
            if (t >= off) s += u;
        }
        wsum[t] = s;
    }
    __syncthreads();
    int woff = (wid == 0) ? 0 : wsum[wid - 1];
    if (i < n) starts[i] = woff + incl - v;
    if (t == 0) blockSum[blockIdx.x] = wsum[15];
}

// ---------- 2b) scan block sums ----------
__global__ __launch_bounds__(1024) void scan2_kernel(
    const int* __restrict__ blockSum, int* __restrict__ blockOff,
    int* __restrict__ starts, int nb, int n)
{
    __shared__ int arr[1024];
    int t = threadIdx.x;
    int v = (t < nb) ? blockSum[t] : 0;
    arr[t] = v;
    __syncthreads();
    #pragma unroll
    for (int off = 1; off < 1024; off <<= 1) {
        int x = (t >= off) ? arr[t - off] : 0;
        __syncthreads();
        arr[t] += x;
        __syncthreads();
    }
    if (t < nb) blockOff[t] = arr[t] - v;
    if (t == 0) starts[n] = arr[nb - 1];
}

// ---------- 2c) add offsets ----------
__global__ __launch_bounds__(1024) void scan3_kernel(
    int* __restrict__ starts, int* __restrict__ cursor,
    const int* __restrict__ blockOff, int n)
{
    int i = blockIdx.x * 1024 + threadIdx.x;
    if (i < n) {
        int s = starts[i] + blockOff[blockIdx.x];
        starts[i] = s;
        cursor[i] = s;
    }
}

// ---------- 3) XCD-partitioned scatter, fp16x4 payload (8B) ----------
__global__ __launch_bounds__(256) void scatter2_kernel(
    const float* __restrict__ R, const int* __restrict__ idx,
    int* __restrict__ cursor, h16x4* __restrict__ sorted, int nEdges, int nAtoms)
{
    int g  = blockIdx.x & 7;
    int gb = blockIdx.x >> 3;
    int per = (nAtoms + 7) >> 3;
    int lo = g * per;
    int hi = lo + per; if (hi > nAtoms) hi = nAtoms;

    auto emit = [&](int i, int j) {
        if (i < lo || i >= hi) return;
        float rix = R[3*(size_t)i], riy = R[3*(size_t)i+1], riz = R[3*(size_t)i+2];
        float rjx = R[3*(size_t)j], rjy = R[3*(size_t)j+1], rjz = R[3*(size_t)j+2];
        float dx = rjx - rix, dy = rjy - riy, dz = rjz - riz;
        float r = sqrtf(dx*dx + dy*dy + dz*dz);
        float inv = 1.0f / (r + 1e-8f);
        int pos = atomicAdd(&cursor[i], 1);
        h16x4 v = { (_Float16)r, (_Float16)(dx*inv), (_Float16)(dy*inv), (_Float16)(dz*inv) };
        sorted[pos] = v;
    };

    if ((nEdges & 3) == 0) {
        int nq = nEdges >> 2;
        const int4* i4p = (const int4*)idx;
        const int4* j4p = (const int4*)(idx + nEdges);
        for (int q = gb * 256 + threadIdx.x; q < nq; q += NBG * 256) {
            int4 iv = i4p[q], jv = j4p[q];
            emit(iv.x, jv.x); emit(iv.y, jv.y);
            emit(iv.z, jv.z); emit(iv.w, jv.w);
        }
    } else {
        for (int e = gb * 256 + threadIdx.x; e < nEdges; e += NBG * 256)
            emit(idx[e], idx[nEdges + e]);
    }
}

// ---------- 4) segmented reduce (fp16x4 payload) + fused folded-feat (fp8 out) ----------
__global__ __launch_bounds__(256) void accum_kernel(
    const h16x4* __restrict__ sorted, const int* __restrict__ starts,
    const float* __restrict__ centers, const float* __restrict__ width,
    float* __restrict__ M0M1, unsigned char* __restrict__ feat8,
    int nAtoms, int useFeat)
{
    __shared__ float sm[4][64];
    int wv = threadIdx.x >> 6, lane = threadIdx.x & 63;
    int atom = blockIdx.x * 4 + wv;
    if (atom >= nAtoms) return;
    int s = starts[atom], e = starts[atom + 1];
    int k = lane >> 2, c = lane & 3;
    float ck = centers[k];
    float w = width[0];
    float inv2w2 = 1.0f / (2.0f * w * w);
    float acc = 0.0f;
    auto term = [&](h16x4 v) {
        float r = (float)v[0];
        float diff = r - ck;
        float b = __expf(-diff * diff * inv2w2);
        float comp = (c == 0) ? 1.0f : ((c == 1) ? (float)v[1] : ((c == 2) ? (float)v[2] : (float)v[3]));
        return b * comp;
    };
    int p = s;
    for (; p + 3 < e; p += 4) {
        h16x4 v0 = sorted[p];
        h16x4 v1 = sorted[p + 1];
        h16x4 v2 = sorted[p + 2];
        h16x4 v3 = sorted[p + 3];
        acc += term(v0); acc += term(v1); acc += term(v2); acc += term(v3);
    }
    for (; p < e; ++p) acc += term(sorted[p]);

    if (!useFeat) {
        M0M1[(size_t)atom * 64 + lane] = acc;
        return;
    }
    sm[wv][lane] = acc;
    asm volatile("s_waitcnt lgkmcnt(0)" ::: "memory");
    unsigned char* frow = feat8 + (size_t)atom * K1F;
    #pragma unroll
    for (int q = 0; q < 3; ++q) {
        int idx5 = q * 64 + lane;
        if (idx5 >= K1F) break;
        float val;
        if (idx5 < 16) {
            val = sm[wv][4 * idx5];
        } else if (idx5 < 152) {
            int a, b;
            tri_ab(idx5 - 16, a, b);
            val = sm[wv][4*a+1] * sm[wv][4*b+1]
                + sm[wv][4*a+2] * sm[wv][4*b+2]
                + sm[wv][4*a+3] * sm[wv][4*b+3];
        } else {
            val = 0.0f;
        }
        frow[idx5] = f2fp8(val);
    }
}

// ---------- W -> bf16 transposed (fallback W1t + W2t) ----------
__global__ __launch_bounds__(256) void convW_kernel(
    const float* __restrict__ W, short* __restrict__ Wt, int K, int Kpad, int N)
{
    int n = blockIdx.x * 256 + threadIdx.x;
    int k = blockIdx.y;
    if (n >= N) return;
    float v = (k < K) ? W[(size_t)k * N + n] : 0.0f;
    Wt[(size_t)n * Kpad + k] = f2bf(v);
}

// ---------- W1 -> folded fp8 transposed, pre-scaled x16: W1f8[n][160] ----------
__global__ __launch_bounds__(256) void convW1f8_kernel(
    const float* __restrict__ W, unsigned char* __restrict__ Wf, int N)
{
    int n = blockIdx.x * 256 + threadIdx.x;
    int k = blockIdx.y;
    if (n >= N) return;
    float v;
    if (k < 16) {
        v = W[(size_t)k * N + n];
    } else if (k < 152) {
        int a, b;
        tri_ab(k - 16, a, b);
        v = W[(size_t)(16 + a*16 + b) * N + n];
        if (b > a) v += W[(size_t)(16 + b*16 + a) * N + n];
    } else {
        v = 0.0f;
    }
    Wf[(size_t)n * K1F + k] = f2fp8(v * 16.0f);
}

// ---------- W2 -> fp8 e4m3 transposed, pre-scaled x16: W2f8[n][512] ----------
__global__ __launch_bounds__(256) void convW2f8_kernel(
    const float* __restrict__ W, unsigned char* __restrict__ Wf, int N)
{
    int n = blockIdx.x * 256 + threadIdx.x;
    int k = blockIdx.y;
    if (n >= N) return;
    Wf[(size_t)n * HID + k] = f2fp8(W[(size_t)k * N + n] * 16.0f);
}

// ============ GEMM1 fallback (R10 verbatim, bf16 h1; unused in fp8 path) ============
__global__ __launch_bounds__(256, 2) void gemm1_mfma(
    const float* __restrict__ M0M1, const short* __restrict__ W1t,
    const float* __restrict__ bias, short* __restrict__ C, int M, int nwg)
{
    __shared__ float MsT[64][128];
    __shared__ short Asl[2][4096];
    __shared__ short Bsl[4][4096];
    int t = threadIdx.x;
    int w = t >> 6, lane = t & 63;
    int wr = w >> 1, wc = w & 1;
    int li = lane & 15, lg = lane >> 4;
    int lin = xcd_swz(blockIdx.x, nwg);
    int row0 = (lin >> 2) * 128;
    int col0 = (lin & 3) * 128;

    {
        int mrow = t >> 1, mo = (t & 1) * 32;
        int gm = row0 + mrow; if (gm > M - 1) gm = M - 1;
        const float4* src = (const float4*)(M0M1 + (size_t)gm * 64 + mo);
        #pragma unroll
        for (int q = 0; q < 8; ++q) {
            float4 v = src[q];
            int c0 = mo + q * 4;
            MsT[c0+0][mrow] = v.x; MsT[c0+1][mrow] = v.y;
            MsT[c0+2][mrow] = v.z; MsT[c0+3][mrow] = v.w;
        }
    }
    __syncthreads();

    auto stageA = [&](int kt, int buf) {
        #pragma unroll
        for (int p = 0; p < 2; ++p) {
            int cell = p * 256 + t;
            int k8 = cell >> 7, row = cell & 127;
            int kbase = kt * 32 + k8 * 8;
            bf16x8 v;
            if (kbase < 16) {
                #pragma unroll
                for (int j = 0; j < 8; ++j) v[j] = f2bf(MsT[4*(kbase+j)][row]);
            } else if (kbase < 272) {
                int g = kbase - 16, a = g >> 4, b0 = g & 15;
                float ax = MsT[4*a+1][row], ay = MsT[4*a+2][row], az = MsT[4*a+3][row];
                #pragma unroll
                for (int j = 0; j < 8; ++j) {
                    int b = b0 + j;
                    v[j] = f2bf(ax*MsT[4*b+1][row] + ay*MsT[4*b+2][row] + az*MsT[4*b+3][row]);
                }
            } else {
                #pragma unroll
                for (int j = 0; j < 8; ++j) v[j] = 0;
            }
            *(bf16x8*)&Asl[buf][cell * 8] = v;
        }
    };
    auto stageB = [&](int kt, int buf) {
        #pragma unroll
        for (int p = 0; p < 2; ++p) {
            int cell = p * 256 + t;
            int k8 = cell >> 7, col = cell & 127;
            const short* src = W1t + (size_t)(col0 + col) * K1P + kt*32 + k8*8;
            gl_lds16(src, &Bsl[buf][(p * 256 + w * 64) * 8]);
        }
    };

    f32x4 acc[4][4] = {};
    const int NS = K1P / 32;
    stageA(0, 0);
    stageB(0, 0); stageB(1, 1); stageB(2, 2);

    #pragma unroll
    for (int s = 0; s < NS; ++s) {
        if (s <= NS - 3)      asm volatile("s_waitcnt vmcnt(4) lgkmcnt(0)\n\ts_barrier" ::: "memory");
        else if (s == NS - 2) asm volatile("s_waitcnt vmcnt(2) lgkmcnt(0)\n\ts_barrier" ::: "memory");
        else                  asm volatile("s_waitcnt vmcnt(0) lgkmcnt(0)\n\ts_barrier" ::: "memory");
        if (s + 3 < NS) stageB(s + 3, (s + 3) & 3);
        bf16x8 af[4], bfr[4];
        #pragma unroll
        for (int m = 0; m < 4; ++m)
            af[m] = *(const bf16x8*)&Asl[s & 1][(lg*128 + wr*64 + m*16 + li) * 8];
        #pragma unroll
        for (int n = 0; n < 4; ++n)
            bfr[n] = *(const bf16x8*)&Bsl[s & 3][(lg*128 + wc*64 + n*16 + li) * 8];
        if (s + 1 < NS) stageA(s + 1, (s + 1) & 1);
        __builtin_amdgcn_s_setprio(1);
        #pragma unroll
        for (int m = 0; m < 4; ++m)
            #pragma unroll
            for (int n = 0; n < 4; ++n)
                acc[m][n] = __builtin_amdgcn_mfma_f32_16x16x32_bf16(af[m], bfr[n], acc[m][n], 0, 0, 0);
        __builtin_amdgcn_s_setprio(0);
    }

    float bv[4];
    #pragma unroll
    for (int n = 0; n < 4; ++n) bv[n] = bias[col0 + wc*64 + n*16 + li];
    #pragma unroll
    for (int m = 0; m < 4; ++m)
        #pragma unroll
        for (int r = 0; r < 4; ++r) {
            int row = row0 + wr*64 + m*16 + lg*4 + r;
            if (row >= M) continue;
            size_t base = (size_t)row * HID + col0 + wc*64 + li;
            #pragma unroll
            for (int n = 0; n < 4; ++n) {
                float cx = acc[m][n][r] + bv[n];
                C[base + n*16] = f2bf(silu(cx));
            }
        }
}

// ============ GEMM1 fp8 (NS=5, BK=32): h1 = silu(feat8 @ W1f8/16 + b1) ============
__global__ __launch_bounds__(256, 3) void gemm_feat_fp8(
    const unsigned char* __restrict__ F, const unsigned char* __restrict__ W1f8,
    const float* __restrict__ bias, unsigned char* __restrict__ C, int M, int nwg)
{
    __shared__ __align__(16) unsigned char Asl[3][4096];
    __shared__ __align__(16) unsigned char Bsl[3][4096];
    int t = threadIdx.x;
    int w = t >> 6, lane = t & 63;
    int wr = w >> 1, wc = w & 1;
    int li = lane & 15, lg = lane >> 4;
    int lin = xcd_swz(blockIdx.x, nwg);
    int row0 = (lin >> 2) * 128;
    int col0 = (lin & 3) * 128;

    int rr = t & 127, k16 = t >> 7;
    int grA = row0 + rr; if (grA > M - 1) grA = M - 1;
    const unsigned char* aSrc = F + (size_t)grA * K1F + k16 * 16;
    const unsigned char* bSrc = W1f8 + (size_t)(col0 + rr) * K1F + k16 * 16;

    auto stage = [&](int kt, int buf) {
        gl_lds16(aSrc + kt * 32, &Asl[buf][w * 1024]);
        gl_lds16(bSrc + kt * 32, &Bsl[buf][w * 1024]);
    };

    f32x4 acc[4][4] = {};
    const int NS = K1F / 32;   // 5
    stage(0, 0); stage(1, 1);

    #pragma unroll
    for (int s = 0; s < NS; ++s) {
        if (s < NS - 1) asm volatile("s_waitcnt vmcnt(2)\n\ts_barrier" ::: "memory");
        else            asm volatile("s_waitcnt vmcnt(0)\n\ts_barrier" ::: "memory");
        if (s + 2 < NS) stage(s + 2, (s + 2) % 3);
        long af[4], bfr[4];
        const unsigned char* Ab = &Asl[s % 3][(lg >> 1) * 2048 + (lg & 1) * 8 + (wr*64 + li) * 16];
        const unsigned char* Bb = &Bsl[s % 3][(lg >> 1) * 2048 + (lg & 1) * 8 + (wc*64 + li) * 16];
        #pragma unroll
        for (int m = 0; m < 4; ++m) af[m] = *(const long*)(Ab + m * 256);
        #pragma unroll
        for (int n = 0; n < 4; ++n) bfr[n] = *(const long*)(Bb + n * 256);
        __builtin_amdgcn_s_setprio(1);
        #pragma unroll
        for (int m = 0; m < 4; ++m)
            #pragma unroll
            for (int n = 0; n < 4; ++n)
                acc[m][n] = __builtin_amdgcn_mfma_f32_16x16x32_fp8_fp8(af[m], bfr[n], acc[m][n], 0, 0, 0);
        __builtin_amdgcn_s_setprio(0);
    }

    float bv[4];
    #pragma unroll
    for (int n = 0; n < 4; ++n) bv[n] = bias[col0 + wc*64 + n*16 + li];
    #pragma unroll
    for (int m = 0; m < 4; ++m)
        #pragma unroll
        for (int r = 0; r < 4; ++r) {
            int row = row0 + wr*64 + m*16 + lg*4 + r;
            if (row >= M) continue;
            size_t base = (size_t)row * HID + col0 + wc*64 + li;
            #pragma unroll
            for (int n = 0; n < 4; ++n) {
                float cx = acc[m][n][r] * 0.0625f + bv[n];   // undo W1 x16 pre-scale
                C[base + n*16] = f2fp8(silu(cx));
            }
        }
}

// ============ GEMM2 fp8 v3: 128x128, BK=64 (8 barrier drains), 3-buf/1-ahead ============
// LDS per buf: 4 k16-units x [128 rows x 16B]; unit stride 2048.
// Wave w stages rows (w&1)*64+lane of units (w>>1) and (w>>1)+2.
__global__ __launch_bounds__(256, 3) void gemm2_fp8(
    const unsigned char* __restrict__ A, const unsigned char* __restrict__ W2f,
    const float* __restrict__ bias, const float* __restrict__ W3,
    const float* __restrict__ b3, const float* __restrict__ scale,
    const float* __restrict__ shift, const int* __restrict__ Z,
    float* __restrict__ out, int M, int nwg)
{
    __shared__ __align__(16) unsigned char Asl[3][8192];
    __shared__ __align__(16) unsigned char Bsl[3][8192];
    __shared__ float rsum[2][128];
    __shared__ float red[4];
    int t = threadIdx.x;
    int w = t >> 6, lane = t & 63;
    int wr = w >> 1, wc = w & 1;
    int li = lane & 15, lg = lane >> 4;
    int lin = xcd_swz(blockIdx.x, nwg);
    int row0 = (lin >> 2) * 128;
    int col0 = (lin & 3) * 128;

    int rr = t & 127, k16 = t >> 7;   // k16 == w>>1 (wave-uniform)
    int grA = row0 + rr; if (grA > M - 1) grA = M - 1;
    const unsigned char* aSrc = A + (size_t)grA * HID + k16 * 16;
    const unsigned char* bSrc = W2f + (size_t)(col0 + rr) * HID + k16 * 16;

    auto stage = [&](int kt, int buf) {   // 4 gl_lds per thread, BK=64 (kt in [0,8))
        int b0 = (w >> 1) * 2048 + (w & 1) * 1024;
        gl_lds16(aSrc + kt * 64,      &Asl[buf][b0]);
        gl_lds16(aSrc + kt * 64 + 32, &Asl[buf][b0 + 2 * 2048]);
        gl_lds16(bSrc + kt * 64,      &Bsl[buf][b0]);
        gl_lds16(bSrc + kt * 64 + 32, &Bsl[buf][b0 + 2 * 2048]);
    };

    f32x4 acc[4][4] = {};
    const int NS = HID / 64;   // 8
    stage(0, 0); stage(1, 1);  // 8 loads in flight

    for (int s = 0; s < NS; ++s) {
        if (s < NS - 1) asm volatile("s_waitcnt vmcnt(4)\n\ts_barrier" ::: "memory");
        else            asm volatile("s_waitcnt vmcnt(0)\n\ts_barrier" ::: "memory");
        if (s + 2 < NS) stage(s + 2, (s + 2) % 3);
        #pragma unroll
        for (int kk = 0; kk < 2; ++kk) {
            long af[4], bfr[4];
            const unsigned char* Ab = &Asl[s % 3][(kk*2 + (lg >> 1)) * 2048 + (lg & 1) * 8 + (wr*64 + li) * 16];
            const unsigned char* Bb = &Bsl[s % 3][(kk*2 + (lg >> 1)) * 2048 + (lg & 1) * 8 + (wc*64 + li) * 16];
            #pragma unroll
            for (int m = 0; m < 4; ++m) af[m] = *(const long*)(Ab + m * 256);
            #pragma unroll
            for (int n = 0; n < 4; ++n) bfr[n] = *(const long*)(Bb + n * 256);
            __builtin_amdgcn_s_setprio(1);
            #pragma unroll
            for (int m = 0; m < 4; ++m)
                #pragma unroll
                for (int n = 0; n < 4; ++n)
                    acc[m][n] = __builtin_amdgcn_mfma_f32_16x16x32_fp8_fp8(af[m], bfr[n], acc[m][n], 0, 0, 0);
            __builtin_amdgcn_s_setprio(0);
        }
    }

    float bv[4], w3v[4];
    #pragma unroll
    for (int n = 0; n < 4; ++n) {
        int col = col0 + wc*64 + n*16 + li;
        bv[n]  = bias[col];
        w3v[n] = W3[col];
    }
    #pragma unroll
    for (int m = 0; m < 4; ++m)
        #pragma unroll
        for (int r = 0; r < 4; ++r) {
            float s = 0.f;
            #pragma unroll
            for (int n = 0; n < 4; ++n) {
                float cx = acc[m][n][r] * 0.0625f + bv[n];   // undo W2 x16 pre-scale
                s += silu(cx) * w3v[n];
            }
            #pragma unroll
            for (int off = 1; off < 16; off <<= 1) s += __shfl_xor(s, off);
            if (li == 0) rsum[wc][wr*64 + m*16 + lg*4 + r] = s;
        }
    __syncthreads();
    float e = 0.f;
    if (t < 128) {
        int row = row0 + t;
        if (row < M) {
            float v = rsum[0][t] + rsum[1][t];
            int z = Z[row];
            e = scale[z] * v;
            if ((lin & 3) == 0) e += scale[z] * b3[0] + shift[z];
        }
    }
    #pragma unroll
    for (int off = 32; off > 0; off >>= 1) e += __shfl_down(e, off);
    if (lane == 0) red[w] = e;
    __syncthreads();
    if (t == 0) atomicAdd(out, red[0] + red[1] + red[2] + red[3]);
}

// ============ GEMM2 bf16 fallback (R16 verbatim) ============
__global__ __launch_bounds__(256, 3) void gemm2_mfma(
    const short* __restrict__ A, const short* __restrict__ W2t,
    const float* __restrict__ bias, const float* __restrict__ W3,
    const float* __restrict__ b3, const float* __restrict__ scale,
    const float* __restrict__ shift, const int* __restrict__ Z,
    float* __restrict__ out, int M, int nwg)
{
    __shared__ short Asl[3][4096];
    __shared__ short Bsl[3][4096];
    __shared__ float rsum[2][128];
    __shared__ float red[4];
    int t = threadIdx.x;
    int w = t >> 6, lane = t & 63;
    int wr = w >> 1, wc = w & 1;
    int li = lane & 15, lg = lane >> 4;
    int lin = xcd_swz(blockIdx.x, nwg);
    int row0 = (lin >> 2) * 128;
    int col0 = (lin & 3) * 128;

    int rr = t & 127, k8h = t >> 7;
    int grA = row0 + rr; if (grA > M - 1) grA = M - 1;
    const short* aSrc0 = A + (size_t)grA * HID + k8h * 8;
    const short* aSrc1 = aSrc0 + 16;
    const short* bSrc0 = W2t + (size_t)(col0 + rr) * HID + k8h * 8;
    const short* bSrc1 = bSrc0 + 16;

    auto stage = [&](int kt, int buf) {
        gl_lds16(aSrc0 + kt * 32, &Asl[buf][(w * 64) * 8]);
        gl_lds16(aSrc1 + kt * 32, &Asl[buf][(256 + w * 64) * 8]);
        gl_lds16(bSrc0 + kt * 32, &Bsl[buf][(w * 64) * 8]);
        gl_lds16(bSrc1 + kt * 32, &Bsl[buf][(256 + w * 64) * 8]);
    };

    f32x4 acc[4][4] = {};
    const int NS = HID / 32;
    stage(0, 0); stage(1, 1);

    for (int s = 0; s < NS; ++s) {
        if (s < NS - 1) asm volatile("s_waitcnt vmcnt(4)\n\ts_barrier" ::: "memory");
        else            asm volatile("s_waitcnt vmcnt(0)\n\ts_barrier" ::: "memory");
        if (s + 2 < NS) stage(s + 2, (s + 2) % 3);
        bf16x8 af[4], bfr[4];
        #pragma unroll
        for (int m = 0; m < 4; ++m)
            af[m] = *(const bf16x8*)&Asl[s % 3][(lg*128 + wr*64 + m*16 + li) * 8];
        #pragma unroll
        for (int n = 0; n < 4; ++n)
            bfr[n] = *(const bf16x8*)&Bsl[s % 3][(lg*128 + wc*64 + n*16 + li) * 8];
        __builtin_amdgcn_s_setprio(1);
        #pragma unroll
        for (int m = 0; m < 4; ++m)
            #pragma unroll
            for (int n = 0; n < 4; ++n)
                acc[m][n] = __builtin_amdgcn_mfma_f32_16x16x32_bf16(af[m], bfr[n], acc[m][n], 0, 0, 0);
        __builtin_amdgcn_s_setprio(0);
    }

    float bv[4], w3v[4];
    #pragma unroll
    for (int n = 0; n < 4; ++n) {
        int col = col0 + wc*64 + n*16 + li;
        bv[n]  = bias[col];
        w3v[n] = W3[col];
    }
    #pragma unroll
    for (int m = 0; m < 4; ++m)
        #pragma unroll
        for (int r = 0; r < 4; ++r) {
            float s = 0.f;
            #pragma unroll
            for (int n = 0; n < 4; ++n) {
                float cx = acc[m][n][r] + bv[n];
                s += silu(cx) * w3v[n];
            }
            #pragma unroll
            for (int off = 1; off < 16; off <<= 1) s += __shfl_xor(s, off);
            if (li == 0) rsum[wc][wr*64 + m*16 + lg*4 + r] = s;
        }
    __syncthreads();
    float e = 0.f;
    if (t < 128) {
        int row = row0 + t;
        if (row < M) {
            float v = rsum[0][t] + rsum[1][t];
            int z = Z[row];
            e = scale[z] * v;
            if ((lin & 3) == 0) e += scale[z] * b3[0] + shift[z];
        }
    }
    #pragma unroll
    for (int off = 32; off > 0; off >>= 1) e += __shfl_down(e, off);
    if (lane == 0) red[w] = e;
    __syncthreads();
    if (t == 0) atomicAdd(out, red[0] + red[1] + red[2] + red[3]);
}

extern "C" void kernel_launch(void* const* d_in, const int* in_sizes, int n_in,
                              void* d_out, int out_size, void* d_ws, size_t ws_size,
                              hipStream_t stream)
{
    const float* R       = (const float*)d_in[0];
    const int*   Z       = (const int*)  d_in[1];
    const int*   idx     = (const int*)  d_in[2];
    const float* centers = (const float*)d_in[5];
    const float* width   = (const float*)d_in[6];
    const float* W1      = (const float*)d_in[7];
    const float* b1      = (const float*)d_in[8];
    const float* W2      = (const float*)d_in[9];
    const float* b2      = (const float*)d_in[10];
    const float* W3      = (const float*)d_in[11];
    const float* b3      = (const float*)d_in[12];
    const float* scale   = (const float*)d_in[13];
    const float* shift   = (const float*)d_in[14];

    int nAtoms = in_sizes[0] / 3;
    int nEdges = in_sizes[2] / 2;

    size_t m0m1_b = (size_t)nAtoms * 64 * sizeof(float);   // 25.6 MB
    size_t h1_b   = (size_t)nAtoms * HID * 2;              // 102.4 MB region
    size_t w1t_b  = (size_t)HID * K1P * 2;                 // 288 KB
    size_t w2t_b  = (size_t)HID * HID * 2;                 // 512 KB
    size_t w1f_b  = (size_t)HID * K1F;                     // 80 KB (fp8)
    size_t w2f8_b = (size_t)HID * HID;                     // 256 KB
    size_t feat_b = (size_t)nAtoms * K1F;                  // 16 MB (fp8)
    if (ws_size < m0m1_b + h1_b + w1t_b + w2t_b) return;
    int useFeat = (ws_size >= m0m1_b + h1_b + w1t_b + w2t_b + w1f_b + w2f8_b + feat_b) ? 1 : 0;

    char* ws = (char*)d_ws;
    float* M0M1  = (float*)ws;
    char*  regB  = ws + m0m1_b;
    short* h1    = (short*)regB;                  // bf16 fallback
    unsigned char* h1f8 = (unsigned char*)regB;   // fp8 path
    short* W1t   = (short*)(ws + m0m1_b + h1_b);
    short* W2t   = W1t + (size_t)HID * K1P;
    unsigned char* W1f8 = (unsigned char*)(W2t + (size_t)HID * HID);
    unsigned char* W2f8 = W1f8 + (size_t)HID * K1F;
    unsigned char* feat8 = (unsigned char*)(ws + m0m1_b + h1_b + w1t_b + w2t_b + w1f_b + w2f8_b);

    int nb = (nAtoms + 1023) / 1024;
    size_t sorted_b = (size_t)nEdges * sizeof(h16x4);      // 12.8 MB
    h16x4* sorted = (h16x4*)regB;
    int* counts   = (int*)(regB + sorted_b);
    int* starts   = counts + nAtoms;
    int* cursor   = starts + nAtoms + 1;
    int* blockSum = cursor + nAtoms;
    int* blockOff = blockSum + nb;
    if (sorted_b + (size_t)(3 * nAtoms + 1 + 2 * nb) * sizeof(int) > h1_b) return;

    float* out = (float*)d_out;

    hipMemsetAsync(counts, 0, (size_t)nAtoms * sizeof(int), stream);
    hipMemsetAsync(out, 0, sizeof(float), stream);

    if (useFeat) {
        convW1f8_kernel<<<dim3(2, K1F), 256, 0, stream>>>(W1, W1f8, HID);
        convW2f8_kernel<<<dim3(2, HID), 256, 0, stream>>>(W2, W2f8, HID);
    } else {
        convW_kernel<<<dim3(2, K1P), 256, 0, stream>>>(W1, W1t, 272, K1P, HID);
        convW_kernel<<<dim3(2, HID), 256, 0, stream>>>(W2, W2t, HID, HID, HID);
    }

    int vec4 = ((nEdges & 3) == 0) ? 1 : 0;
    int hb = vec4 ? ((nEdges / 4) + 255) / 256 : (nEdges + 255) / 256;
    hist_kernel <<<hb, 256, 0, stream>>>(idx, counts, nEdges, vec4);
    scan1_kernel<<<nb, 1024, 0, stream>>>(counts, starts, blockSum, nAtoms);
    scan2_kernel<<<1, 1024, 0, stream>>>(blockSum, blockOff, starts, nb, nAtoms);
    scan3_kernel<<<nb, 1024, 0, stream>>>(starts, cursor, blockOff, nAtoms);
    scatter2_kernel<<<8 * NBG, 256, 0, stream>>>(R, idx, cursor, sorted, nEdges, nAtoms);
    accum_kernel<<<(nAtoms + 3) / 4, 256, 0, stream>>>(sorted, starts, centers, width,
                                                       M0M1, feat8, nAtoms, useFeat);

    int gb = (nAtoms + 127) / 128;   // 782 row-blocks
    int nwg = gb * 4;                // x4 col-blocks, col-fast in lin order
    if (useFeat) {
        gemm_feat_fp8<<<nwg, 256, 0, stream>>>(feat8, W1f8, b1, h1f8, nAtoms, nwg);
        gemm2_fp8<<<nwg, 256, 0, stream>>>(h1f8, W2f8, b2, W3, b3, scale, shift, Z, out, nAtoms, nwg);
    } else {
        gemm1_mfma<<<nwg, 256, 0, stream>>>(M0M1, W1t, b1, h1, nAtoms, nwg);
        gemm2_mfma<<<nwg, 256, 0, stream>>>(h1, W2t, b2, W3, b3, scale, shift, Z, out, nAtoms, nwg);
    }
}